// Round 1
// 712.273 us; speedup vs baseline: 1.1008x; 1.1008x over previous
//
#include <hip/hip_runtime.h>
#include <stdint.h>

#define NB 32
#define FC 1024
#define DD 512
#define HH 1024
#define BN_EPS 1e-5f

typedef unsigned short u16;
typedef unsigned int u32;
typedef __attribute__((ext_vector_type(8))) short bf16x8;   // 8 bf16 = 4 VGPRs
typedef __attribute__((ext_vector_type(4))) float f32x4;
typedef __attribute__((ext_vector_type(8))) unsigned short ushort8v;

#define AS1 __attribute__((address_space(1)))
#define AS3 __attribute__((address_space(3)))

__device__ __forceinline__ float b2f(u16 u) {
    union { u32 i; float f; } v;
    v.i = ((u32)u) << 16;
    return v.f;
}
__device__ __forceinline__ u16 f2b(float f) {
    union { float f; u32 i; } v;
    v.f = f;
    const u32 b = v.i;
    return (u16)((b + 0x7FFFu + ((b >> 16) & 1u)) >> 16);
}

// async global->LDS, 16B per lane; lds dest must be wave-uniform base
__device__ __forceinline__ void gld16(const u16* g, u16* l) {
    __builtin_amdgcn_global_load_lds((const AS1 u32*)g, (AS3 u32*)l, 16, 0, 0);
}

// XCD-aware tile swizzle: lin%8 = XCD slab over (m,z); each XCD iterates n
// fastest within its slab -> A-tile reuse lands in one XCD's L2.
__device__ __forceinline__ void swizzle_tiles(int& mt, int& nt, int& zt) {
    const int gx = gridDim.x, gy = gridDim.y, gz = gridDim.z;
    const int mzTot = gy * gz;
    if ((mzTot & 7) != 0) { nt = blockIdx.x; mt = blockIdx.y; zt = blockIdx.z; return; }
    long lin = ((long)blockIdx.z * gy + blockIdx.y) * gx + blockIdx.x;
    const int slab = mzTot >> 3;
    const int xcd = (int)(lin & 7);
    const long idx = lin >> 3;
    nt = (int)(idx % gx);
    const int mz = (int)(idx / gx) + xcd * slab;
    mt = mz % gy;
    zt = mz / gy;
}

// ---------------------------------------------------------------------------
// Dtype detection: flag=1 if x is bf16 pairs, 0 if fp32.
// ---------------------------------------------------------------------------
__global__ __launch_bounds__(256) void detect_dtype(
    const u32* __restrict__ x, int* __restrict__ flag)
{
    __shared__ int cnt[256];
    int c = 0;
    for (int i = threadIdx.x; i < 4096; i += 256) {
        const u32 lo = x[i] & 0xFFFFu;
        const u32 e = (lo >> 7) & 0xFFu;
        if (e >= 0x68u && e <= 0x85u) c++;
    }
    cnt[threadIdx.x] = c;
    __syncthreads();
    for (int s = 128; s > 0; s >>= 1) {
        if (threadIdx.x < (unsigned)s) cnt[threadIdx.x] += cnt[threadIdx.x + s];
        __syncthreads();
    }
    if (threadIdx.x == 0) flag[0] = (cnt[0] > 2048) ? 1 : 0;
}

__global__ __launch_bounds__(256) void convert_to_bf16(
    const void* __restrict__ src, u16* __restrict__ dst, long n4,
    const int* __restrict__ flag)
{
    const bool isbf = (*flag != 0);
    long i4 = (long)blockIdx.x * blockDim.x + threadIdx.x;
    const long stride = (long)gridDim.x * blockDim.x;
    for (; i4 < n4; i4 += stride) {
        const long i = i4 << 2;
        if (isbf) {
            *(ushort4*)(dst + i) = *(const ushort4*)((const u16*)src + i);
        } else {
            const float4 v = *(const float4*)((const float*)src + i);
            ushort4 o;
            o.x = f2b(v.x); o.y = f2b(v.y); o.z = f2b(v.z); o.w = f2b(v.w);
            *(ushort4*)(dst + i) = o;
        }
    }
}

// ---------------------------------------------------------------------------
// 256x256 8-phase MFMA GEMM (NT): C[m][n] = sum_k A[m][k]*B[n][k]
//   (+bias[n], softsign). M,N mult of 256; K mult of 64. bf16 in/out, fp32 acc.
// 512 thr = 8 waves (2M x 4N); per-wave 128x64 out = 8x4 frags of 16x16x32.
// LDS 128 KiB = 2 K-tile bufs x {A,B} x {kh0,kh1} 16 KiB regions.
// Per K-tile: 8 phases = (C-quadrant x k-half); each phase: ds_read subtile,
// issue 1 global_load_lds prefetch, s_barrier, MFMA x8 under setprio(1),
// s_barrier. Counted s_waitcnt vmcnt(4) ONLY at phases 4 and 8:
//   p4 retires current tile's kh1 group; p8 retires next tile's kh0 group
//   (vmcnt retires oldest-first; 8 loads/wave in flight max).
// LDS bank swizzle: granule (row r, 16B-granule q) stored at q^((r>>1)&3);
// applied on the GLOBAL source k-offset (gld16 dest stays linear) and on the
// ds_read offset -> each consecutive-8-lane read group hits 8 bank-quads.
// ---------------------------------------------------------------------------
template<bool BIAS, bool SOFTSIGN>
__global__ __launch_bounds__(512, 2) void gemm256_nt(
    const u16* __restrict__ A, const u16* __restrict__ B,
    const u16* __restrict__ bias, u16* __restrict__ C,
    int M, int N, int K, int lda, int ldb, int ldc,
    long sA, long sB, long sC)
{
    extern __shared__ char smem[];

    int mt, nt, zt;
    swizzle_tiles(mt, nt, zt);
    const u16* Ab = A + (long)zt * sA + (long)(mt * 256) * lda;
    const u16* Bb = B + (long)zt * sB + (long)(nt * 256) * ldb;
    C += (long)zt * sC;

    const int tid  = threadIdx.x;
    const int lane = tid & 63;
    const int wv   = tid >> 6;          // 0..7
    const int wr   = (wv >> 2) * 128;   // wave row in tile
    const int wc   = (wv & 3) * 64;     // wave col in tile
    const int lm   = lane & 15;
    const int q    = lane >> 4;

    // ---- swizzled read byte-offsets within a 16 KiB [256r][32k] region ----
    int aOff[2][4], bOff[2][2];
    #pragma unroll
    for (int mh = 0; mh < 2; ++mh)
        #pragma unroll
        for (int i = 0; i < 4; ++i) {
            const int r = wr + mh * 64 + i * 16 + lm;
            aOff[mh][i] = r * 64 + ((q ^ ((r >> 1) & 3)) << 4);
        }
    #pragma unroll
    for (int nh = 0; nh < 2; ++nh)
        #pragma unroll
        for (int j = 0; j < 2; ++j) {
            const int r = wc + nh * 32 + j * 16 + lm;
            bOff[nh][j] = r * 64 + ((q ^ ((r >> 1) & 3)) << 4);
        }

    // ---- staging: wave w covers region rows 32w..32w+31 (2 calls x 1 KiB) --
    // gld16 dest is linear (base + lane*16); the swizzle is applied by
    // pre-permuting the per-lane GLOBAL k-offset (inverse == same involution).
    const int rw = lane >> 2, qs = lane & 3;
    const u16* pA[2]; const u16* pB[2];
    int ldsC[2];                       // wave-uniform byte offset within region
    #pragma unroll
    for (int c = 0; c < 2; ++c) {
        const int r = wv * 32 + c * 16 + rw;
        const int kq = (qs ^ ((r >> 1) & 3)) << 3;   // swizzled 8-elem granule
        pA[c] = Ab + (long)r * lda + kq;
        pB[c] = Bb + (long)r * ldb + kq;
        ldsC[c] = wv * 2048 + c * 1024;
    }

#define STG(bufOff, op, kh, c, PX, kofs) \
    gld16((PX)[c] + (kofs) + (kh) * 32, \
          (u16*)(smem + (bufOff) + (op) * 32768 + (kh) * 16384 + ldsC[c]))

#define RDA(mh, kk, bo) { \
    const char* base_ = smem + (bo) + (kk) * 16384; \
    a[0] = *(const bf16x8*)(base_ + aOff[mh][0]); \
    a[1] = *(const bf16x8*)(base_ + aOff[mh][1]); \
    a[2] = *(const bf16x8*)(base_ + aOff[mh][2]); \
    a[3] = *(const bf16x8*)(base_ + aOff[mh][3]); }

#define RDB(nh, kk, bo) { \
    const char* base_ = smem + (bo) + 32768 + (kk) * 16384; \
    b[0] = *(const bf16x8*)(base_ + bOff[nh][0]); \
    b[1] = *(const bf16x8*)(base_ + bOff[nh][1]); }

#define MMA(mh, nh) do { \
    __builtin_amdgcn_s_setprio(1); \
    acc[(mh)*4+0][(nh)*2+0] = __builtin_amdgcn_mfma_f32_16x16x32_bf16(a[0], b[0], acc[(mh)*4+0][(nh)*2+0], 0,0,0); \
    acc[(mh)*4+0][(nh)*2+1] = __builtin_amdgcn_mfma_f32_16x16x32_bf16(a[0], b[1], acc[(mh)*4+0][(nh)*2+1], 0,0,0); \
    acc[(mh)*4+1][(nh)*2+0] = __builtin_amdgcn_mfma_f32_16x16x32_bf16(a[1], b[0], acc[(mh)*4+1][(nh)*2+0], 0,0,0); \
    acc[(mh)*4+1][(nh)*2+1] = __builtin_amdgcn_mfma_f32_16x16x32_bf16(a[1], b[1], acc[(mh)*4+1][(nh)*2+1], 0,0,0); \
    acc[(mh)*4+2][(nh)*2+0] = __builtin_amdgcn_mfma_f32_16x16x32_bf16(a[2], b[0], acc[(mh)*4+2][(nh)*2+0], 0,0,0); \
    acc[(mh)*4+2][(nh)*2+1] = __builtin_amdgcn_mfma_f32_16x16x32_bf16(a[2], b[1], acc[(mh)*4+2][(nh)*2+1], 0,0,0); \
    acc[(mh)*4+3][(nh)*2+0] = __builtin_amdgcn_mfma_f32_16x16x32_bf16(a[3], b[0], acc[(mh)*4+3][(nh)*2+0], 0,0,0); \
    acc[(mh)*4+3][(nh)*2+1] = __builtin_amdgcn_mfma_f32_16x16x32_bf16(a[3], b[1], acc[(mh)*4+3][(nh)*2+1], 0,0,0); \
    __builtin_amdgcn_s_setprio(0); \
} while (0)

#define BAR() __builtin_amdgcn_s_barrier()
#define WAIT_VM4() { asm volatile("s_waitcnt vmcnt(4)" ::: "memory"); \
                     __builtin_amdgcn_sched_barrier(0); }

    f32x4 acc[8][4] = {};
    bf16x8 a[4], b[2];

    const int NT = K >> 6;

    // prologue: tile 0 -> buf 0 (kh0 group first, then kh1 group)
    STG(0, 0, 0, 0, pA, 0); STG(0, 0, 0, 1, pA, 0);
    STG(0, 1, 0, 0, pB, 0); STG(0, 1, 0, 1, pB, 0);
    STG(0, 0, 1, 0, pA, 0); STG(0, 0, 1, 1, pA, 0);
    STG(0, 1, 1, 0, pB, 0); STG(0, 1, 1, 1, pB, 0);
    WAIT_VM4();   // kh0 of tile 0 resident; kh1 still in flight
    BAR();

    for (int t = 0; t < NT; ++t) {
        const int bo = (t & 1) * 65536;
        const int bn = ((t + 1) & 1) * 65536;
        const int kn = ((t + 1 < NT) ? (t + 1) : t) * 64;  // clamp last prefetch

        // p1: quad(mh0,nh0) kh0
        RDA(0, 0, bo); RDB(0, 0, bo);
        STG(bn, 0, 0, 0, pA, kn);
        BAR(); MMA(0, 0); BAR();
        // p2: quad(mh0,nh1) kh0
        RDB(1, 0, bo);
        STG(bn, 0, 0, 1, pA, kn);
        BAR(); MMA(0, 1); BAR();
        // p3: quad(mh1,nh1) kh0
        RDA(1, 0, bo);
        STG(bn, 1, 0, 0, pB, kn);
        BAR(); MMA(1, 1); BAR();
        // p4: quad(mh1,nh0) kh0  -- retire current tile's kh1 group
        RDB(0, 0, bo);
        STG(bn, 1, 0, 1, pB, kn);
        WAIT_VM4();
        BAR(); MMA(1, 0); BAR();
        // p5: quad(mh0,nh0) kh1
        RDA(0, 1, bo); RDB(0, 1, bo);
        STG(bn, 0, 1, 0, pA, kn);
        BAR(); MMA(0, 0); BAR();
        // p6: quad(mh0,nh1) kh1
        RDB(1, 1, bo);
        STG(bn, 0, 1, 1, pA, kn);
        BAR(); MMA(0, 1); BAR();
        // p7: quad(mh1,nh1) kh1
        RDA(1, 1, bo);
        STG(bn, 1, 1, 0, pB, kn);
        BAR(); MMA(1, 1); BAR();
        // p8: quad(mh1,nh0) kh1  -- retire next tile's kh0 group
        RDB(0, 1, bo);
        STG(bn, 1, 1, 1, pB, kn);
        WAIT_VM4();
        BAR(); MMA(1, 0); BAR();
    }

#undef STG
#undef RDA
#undef RDB
#undef MMA
#undef BAR
#undef WAIT_VM4

    // epilogue: drain everything (incl. clamped prefetch), reuse LDS for the
    // per-wave repack (8 waves x 16x65 fp32 = 33,280 B), coalesced bf16 stores
    __syncthreads();
    float* rep = (float*)smem + wv * (16 * 65);
    const int rr = lane >> 2;
    const int cg = lane & 3;
    const int m0 = mt * 256;
    const int n0 = nt * 256;
    #pragma unroll
    for (int i = 0; i < 8; ++i) {      // row-frag: row = wr + 16*i
        #pragma unroll
        for (int j = 0; j < 4; ++j) {  // col-frag: col = wc + 16*j
            const int col = 16 * j + lm;
            const float bj = BIAS ? b2f(bias[n0 + wc + col]) : 0.0f;
            #pragma unroll
            for (int r = 0; r < 4; ++r) {
                float v = acc[i][j][r] + bj;
                if (SOFTSIGN) v = v / (1.0f + fabsf(v));
                rep[(q * 4 + r) * 65 + col] = v;
            }
        }
        // intra-wave LDS RAW/WAR: wave-lockstep + per-wave buffer (verified pattern)
        const float* lr = rep + rr * 65 + cg * 16;
        const float4 f0 = *(const float4*)(lr + 0);
        const float4 f1 = *(const float4*)(lr + 4);
        const float4 f2 = *(const float4*)(lr + 8);
        const float4 f3 = *(const float4*)(lr + 12);
        ushort8v o0, o1;
        o0[0] = f2b(f0.x); o0[1] = f2b(f0.y); o0[2] = f2b(f0.z); o0[3] = f2b(f0.w);
        o0[4] = f2b(f1.x); o0[5] = f2b(f1.y); o0[6] = f2b(f1.z); o0[7] = f2b(f1.w);
        o1[0] = f2b(f2.x); o1[1] = f2b(f2.y); o1[2] = f2b(f2.z); o1[3] = f2b(f2.w);
        o1[4] = f2b(f3.x); o1[5] = f2b(f3.y); o1[6] = f2b(f3.z); o1[7] = f2b(f3.w);
        u16* cp = C + (long)(m0 + wr + 16 * i + rr) * ldc + n0 + wc + cg * 16;
        *(ushort8v*)cp = o0;
        *(ushort8v*)(cp + 8) = o1;
    }
}

// ---------------------------------------------------------------------------
// bf16 tiled transpose: src [R][Cc] -> dst [Cc][R] per batch
// ---------------------------------------------------------------------------
__global__ __launch_bounds__(256) void transpose_bf16(
    const u16* __restrict__ src, u16* __restrict__ dst,
    int R, int Cc, long sS, long sD)
{
    __shared__ u16 t[32][33];
    const int bz = blockIdx.z;
    src += (long)bz * sS;
    dst += (long)bz * sD;
    const int c0 = blockIdx.x * 32;
    const int r0 = blockIdx.y * 32;
    const int lx = threadIdx.x & 31;
    const int ly = threadIdx.x >> 5;   // 0..7
    #pragma unroll
    for (int d = 0; d < 32; d += 8)
        t[ly + d][lx] = src[(long)(r0 + ly + d) * Cc + c0 + lx];
    __syncthreads();
    #pragma unroll
    for (int d = 0; d < 32; d += 8)
        dst[(long)(c0 + ly + d) * R + r0 + lx] = t[lx][ly + d];
}

// ---------------------------------------------------------------------------
// BN stats over (N, L) per channel f (layout (N, FC, Lc)). One block/channel.
// ---------------------------------------------------------------------------
__global__ __launch_bounds__(256) void bn_stats(
    const u16* __restrict__ src, const u16* __restrict__ gamma,
    const u16* __restrict__ beta, float* __restrict__ ss,
    int Lc, int nOuter)
{
    const int f = blockIdx.x;
    const long outerStride = (long)FC * Lc;
    const u16* base = src + (long)f * Lc;

    float s1 = 0.f, s2 = 0.f;
    for (int n = 0; n < nOuter; ++n) {
        const u16* p = base + n * outerStride;
        for (int i = (threadIdx.x << 2); i < Lc; i += (blockDim.x << 2)) {
            const ushort4 v = *(const ushort4*)(p + i);
            const float a = b2f(v.x), b = b2f(v.y), c = b2f(v.z), d = b2f(v.w);
            s1 += a + b + c + d;
            s2 += a * a + b * b + c * c + d * d;
        }
    }

    __shared__ float r1[256], r2[256];
    const int tid = threadIdx.x;
    r1[tid] = s1;
    r2[tid] = s2;
    __syncthreads();
    for (int s = 128; s > 0; s >>= 1) {
        if (tid < s) { r1[tid] += r1[tid + s]; r2[tid] += r2[tid + s]; }
        __syncthreads();
    }
    if (tid == 0) {
        const float cnt  = (float)nOuter * (float)Lc;
        const float mean = r1[0] / cnt;
        const float var  = r2[0] / cnt - mean * mean;
        const float rstd = rsqrtf(var + BN_EPS);
        const float sc   = b2f(gamma[f]) * rstd;
        ss[f]      = sc;
        ss[FC + f] = b2f(beta[f]) - mean * sc;
    }
}

// dst = src*scale+shift (+ add); add dtype per addflag, dst dtype per outflag
template<bool ADD>
__global__ __launch_bounds__(256) void bn_apply(
    const u16* __restrict__ src, const void* __restrict__ add,
    const int* __restrict__ addflag,
    const float* __restrict__ ss, void* __restrict__ dst,
    const int* __restrict__ outflag, long total4, int Lc)
{
    const bool addf32 = ADD && (addflag != nullptr) && (*addflag == 0);
    const bool outf32 = (outflag != nullptr) && (*outflag == 0);
    long i4 = (long)blockIdx.x * blockDim.x + threadIdx.x;
    const long stride = (long)gridDim.x * blockDim.x;
    for (; i4 < total4; i4 += stride) {
        const long i = i4 << 2;
        const int c = (int)((i / Lc) % FC);
        const float sc = ss[c];
        const float sh = ss[FC + c];
        const ushort4 v = *(const ushort4*)(src + i);
        float o0 = fmaf(b2f(v.x), sc, sh);
        float o1 = fmaf(b2f(v.y), sc, sh);
        float o2 = fmaf(b2f(v.z), sc, sh);
        float o3 = fmaf(b2f(v.w), sc, sh);
        if (ADD) {
            if (addf32) {
                const float4 a = *(const float4*)((const float*)add + i);
                o0 += a.x; o1 += a.y; o2 += a.z; o3 += a.w;
            } else {
                const ushort4 a = *(const ushort4*)((const u16*)add + i);
                o0 += b2f(a.x); o1 += b2f(a.y); o2 += b2f(a.z); o3 += b2f(a.w);
            }
        }
        if (outf32) {
            float4 o; o.x = o0; o.y = o1; o.z = o2; o.w = o3;
            *(float4*)((float*)dst + i) = o;
        } else {
            ushort4 o;
            o.x = f2b(o0); o.y = f2b(o1); o.z = f2b(o2); o.w = f2b(o3);
            *(ushort4*)((u16*)dst + i) = o;
        }
    }
}

// dst = a + b + bias[channel], all bf16
__global__ __launch_bounds__(256) void add3_bias(
    const u16* __restrict__ a, const u16* __restrict__ b,
    const u16* __restrict__ bias, u16* __restrict__ dst,
    long total4, int Lc)
{
    long i4 = (long)blockIdx.x * blockDim.x + threadIdx.x;
    const long stride = (long)gridDim.x * blockDim.x;
    for (; i4 < total4; i4 += stride) {
        const long i = i4 << 2;
        const int c = (int)((i / Lc) % FC);
        const float bs = b2f(bias[c]);
        const ushort4 va = *(const ushort4*)(a + i);
        const ushort4 vb = *(const ushort4*)(b + i);
        ushort4 o;
        o.x = f2b(b2f(va.x) + b2f(vb.x) + bs);
        o.y = f2b(b2f(va.y) + b2f(vb.y) + bs);
        o.z = f2b(b2f(va.z) + b2f(vb.z) + bs);
        o.w = f2b(b2f(va.w) + b2f(vb.w) + bs);
        *(ushort4*)(dst + i) = o;
    }
}

extern "C" void kernel_launch(void* const* d_in, const int* in_sizes, int n_in,
                              void* d_out, int out_size, void* d_ws, size_t ws_size,
                              hipStream_t stream)
{
    const size_t MiB = (size_t)1 << 20;
    const long sFH = (long)FC * HH;        // 1,048,576 elems (2 MiB bf16)
    const long sFF = (long)FC * FC;        // 1,048,576
    const long sFD = (long)FC * DD;        //   524,288 (1 MiB)
    const long VE  = (long)NB * FC * HH;   // 33,554,432 (64 MiB)
    const long PE  = (long)NB * FC * DD;   // 16,777,216 (32 MiB)

    const size_t GLDS = 131072;            // 128 KiB dynamic LDS for gemm256
    static bool s_attr = false;
    if (!s_attr) {
        s_attr = true;
        hipFuncSetAttribute(reinterpret_cast<const void*>(&gemm256_nt<true, false>),
                            hipFuncAttributeMaxDynamicSharedMemorySize, (int)GLDS);
        hipFuncSetAttribute(reinterpret_cast<const void*>(&gemm256_nt<false, true>),
                            hipFuncAttributeMaxDynamicSharedMemorySize, (int)GLDS);
        hipFuncSetAttribute(reinterpret_cast<const void*>(&gemm256_nt<false, false>),
                            hipFuncAttributeMaxDynamicSharedMemorySize, (int)GLDS);
    }

    // bf16 param packing offsets
    long off[16];
    long cur = 0;
    for (int i = 1; i < 15; ++i) { off[i] = cur; cur += ((long)in_sizes[i] + 7) & ~7L; }
    const size_t paramBytes = (size_t)cur * 2;

    // adaptive correlation chunk: scratch = cb*6 MiB (VT + W + V2)
    int cb = 16;
    while (cb > 1 &&
           64 * MiB + (size_t)cb * 6 * MiB + paramBytes + 16384 > ws_size)
        cb >>= 1;

    // ---- workspace layout ----
    u16* V   = (u16*)d_ws;                          // 64 MiB: v (N,F,H)
    u16* VT  = (u16*)((char*)d_ws + 64 * MiB);      // cb*2 MiB: v^T chunk
    u16* WW  = VT + (long)cb * sFH;                 // cb*2 MiB: w chunk
    u16* V2  = WW + (long)cb * sFF;                 // cb*2 MiB: v2 chunk
    u16* WC  = V2 + (long)cb * sFH;                 // packed bf16 params
    char* tail = (char*)(WC + cur);
    tail = (char*)(((uintptr_t)tail + 255) & ~(uintptr_t)255);
    float* SS   = (float*)tail;                     // 8 KiB folded BN
    int*   FLAG = (int*)(SS + 2 * FC);
    // d_out (fp32 out => 64 MiB): lower 32 MiB = VX (v3->s->xr), upper = XB
    u16* VX  = (u16*)d_out;
    u16* XB  = (u16*)d_out + PE;                    // x as bf16
    u16* V4  = V;                                   // v4/t (N,F,D) reuses V
    u16* XRT = V + PE;                              // xr^T reuses V upper half

    const dim3 blk(256);
    const dim3 blk512(512);
    const dim3 egrid(4096);

    // 0. detect dtype; convert params + x to bf16
    detect_dtype<<<1, blk, 0, stream>>>((const u32*)d_in[0], FLAG);
    for (int i = 1; i < 15; ++i) {
        const long n4 = (long)in_sizes[i] / 4;
        int g = (int)((n4 + 255) / 256);
        if (g > 1024) g = 1024;
        if (g < 1) g = 1;
        convert_to_bf16<<<dim3(g), blk, 0, stream>>>(d_in[i], WC + off[i], n4, FLAG);
    }
    convert_to_bf16<<<dim3(1024), blk, 0, stream>>>(d_in[0], XB, PE / 4, FLAG);

    const u16* W0c = WC + off[1];
    const u16* b0c = WC + off[2];
    const u16* g0c = WC + off[3];
    const u16* be0c = WC + off[4];
    const u16* W1c = WC + off[5];
    const u16* b1c = WC + off[6];
    const u16* g1c = WC + off[7];
    const u16* be1c = WC + off[8];
    const u16* gfc = WC + off[9];
    const u16* bfc = WC + off[10];
    const u16* Wcc = WC + off[11];
    const u16* bcc = WC + off[12];
    const u16* goc = WC + off[13];
    const u16* boc = WC + off[14];

    // 1. v = x @ W0^T + b0   (M=32768, N=1024, K=512)
    gemm256_nt<true, false><<<dim3(HH / 256, (NB * FC) / 256, 1), blk512, GLDS, stream>>>(
        XB, W0c, b0c, V, NB * FC, HH, DD, DD, DD, HH, 0, 0, 0);

    // 2-3. v = BN0(v)
    bn_stats<<<FC, blk, 0, stream>>>(V, g0c, be0c, SS, HH, NB);
    bn_apply<false><<<egrid, blk, 0, stream>>>(V, nullptr, nullptr, SS, V, nullptr, VE / 4, HH);

    // 4-6 per chunk: vT; w = softsign(v v^T); v2 = w @ v (via vT); v3 = v2 @ W1^T + b1
    for (int bz0 = 0; bz0 < NB; bz0 += cb) {
        const int c = (NB - bz0 < cb) ? (NB - bz0) : cb;
        transpose_bf16<<<dim3(HH / 32, FC / 32, c), blk, 0, stream>>>(
            V + bz0 * sFH, VT, FC, HH, sFH, sFH);
        gemm256_nt<false, true><<<dim3(FC / 256, FC / 256, c), blk512, GLDS, stream>>>(
            V + bz0 * sFH, V + bz0 * sFH, nullptr, WW,
            FC, FC, HH, HH, HH, FC, sFH, sFH, sFF);
        gemm256_nt<false, false><<<dim3(HH / 256, FC / 256, c), blk512, GLDS, stream>>>(
            WW, VT, nullptr, V2,
            FC, HH, FC, FC, FC, HH, sFF, sFH, sFH);
        gemm256_nt<true, false><<<dim3(DD / 256, (c * FC) / 256, 1), blk512, GLDS, stream>>>(
            V2, W1c, b1c, VX + bz0 * sFD,
            c * FC, DD, HH, HH, HH, DD, 0, 0, 0);
    }

    // 7-8. s = BN1(v3) + x   (in place in VX; x from bf16 copy XB)
    bn_stats<<<FC, blk, 0, stream>>>(VX, g1c, be1c, SS, DD, NB);
    bn_apply<true><<<egrid, blk, 0, stream>>>(VX, XB, nullptr, SS, VX, nullptr, PE / 4, DD);

    // 9-10. xr = BNf(s)      (in place in VX)
    bn_stats<<<FC, blk, 0, stream>>>(VX, gfc, bfc, SS, DD, NB);
    bn_apply<false><<<egrid, blk, 0, stream>>>(VX, nullptr, nullptr, SS, VX, nullptr, PE / 4, DD);

    // 11. xr^T, then v4 = Wc @ xr  (NT via xr^T) -> V4
    transpose_bf16<<<dim3(DD / 32, FC / 32, NB), blk, 0, stream>>>(
        VX, XRT, FC, DD, sFD, sFD);
    gemm256_nt<false, false><<<dim3(DD / 256, FC / 256, NB), blk512, GLDS, stream>>>(
        Wcc, XRT, nullptr, V4, FC, DD, FC, FC, FC, DD, 0, sFD, sFD);

    // 12. t = v4 + bc + xr  (in place V4)
    add3_bias<<<egrid, blk, 0, stream>>>(V4, VX, bcc, V4, PE / 4, DD);

    // 13-14. out = BNo(t); out dtype per FLAG
    bn_stats<<<FC, blk, 0, stream>>>(V4, goc, boc, SS, DD, NB);
    bn_apply<false><<<egrid, blk, 0, stream>>>(V4, nullptr, nullptr, SS, d_out, FLAG, PE / 4, DD);
}

// Round 2
// 690.283 us; speedup vs baseline: 1.1359x; 1.0319x over previous
//
#include <hip/hip_runtime.h>
#include <stdint.h>

#define NB 32
#define FC 1024
#define DD 512
#define HH 1024
#define BN_EPS 1e-5f

typedef unsigned short u16;
typedef unsigned int u32;
typedef __attribute__((ext_vector_type(8))) short bf16x8;   // 8 bf16 = 4 VGPRs
typedef __attribute__((ext_vector_type(4))) float f32x4;
typedef __attribute__((ext_vector_type(8))) unsigned short ushort8v;

#define AS1 __attribute__((address_space(1)))
#define AS3 __attribute__((address_space(3)))

__device__ __forceinline__ float b2f(u16 u) {
    union { u32 i; float f; } v;
    v.i = ((u32)u) << 16;
    return v.f;
}
__device__ __forceinline__ u16 f2b(float f) {
    union { float f; u32 i; } v;
    v.f = f;
    const u32 b = v.i;
    return (u16)((b + 0x7FFFu + ((b >> 16) & 1u)) >> 16);
}

// async global->LDS, 16B per lane; lds dest must be wave-uniform base
__device__ __forceinline__ void gld16(const u16* g, u16* l) {
    __builtin_amdgcn_global_load_lds((const AS1 u32*)g, (AS3 u32*)l, 16, 0, 0);
}

// XCD-aware tile swizzle: lin%8 = XCD slab over (m,z); each XCD iterates n
// fastest within its slab -> A-tile reuse lands in one XCD's L2.
__device__ __forceinline__ void swizzle_tiles(int& mt, int& nt, int& zt) {
    const int gx = gridDim.x, gy = gridDim.y, gz = gridDim.z;
    const int mzTot = gy * gz;
    if ((mzTot & 7) != 0) { nt = blockIdx.x; mt = blockIdx.y; zt = blockIdx.z; return; }
    long lin = ((long)blockIdx.z * gy + blockIdx.y) * gx + blockIdx.x;
    const int slab = mzTot >> 3;
    const int xcd = (int)(lin & 7);
    const long idx = lin >> 3;
    nt = (int)(idx % gx);
    const int mz = (int)(idx / gx) + xcd * slab;
    mt = mz % gy;
    zt = mz / gy;
}

// ---------------------------------------------------------------------------
// Dtype detection: flag=1 if x is bf16 pairs, 0 if fp32.
// ---------------------------------------------------------------------------
__global__ __launch_bounds__(256) void detect_dtype(
    const u32* __restrict__ x, int* __restrict__ flag)
{
    __shared__ int cnt[256];
    int c = 0;
    for (int i = threadIdx.x; i < 4096; i += 256) {
        const u32 lo = x[i] & 0xFFFFu;
        const u32 e = (lo >> 7) & 0xFFu;
        if (e >= 0x68u && e <= 0x85u) c++;
    }
    cnt[threadIdx.x] = c;
    __syncthreads();
    for (int s = 128; s > 0; s >>= 1) {
        if (threadIdx.x < (unsigned)s) cnt[threadIdx.x] += cnt[threadIdx.x + s];
        __syncthreads();
    }
    if (threadIdx.x == 0) flag[0] = (cnt[0] > 2048) ? 1 : 0;
}

__global__ __launch_bounds__(256) void convert_to_bf16(
    const void* __restrict__ src, u16* __restrict__ dst, long n4,
    const int* __restrict__ flag)
{
    const bool isbf = (*flag != 0);
    long i4 = (long)blockIdx.x * blockDim.x + threadIdx.x;
    const long stride = (long)gridDim.x * blockDim.x;
    for (; i4 < n4; i4 += stride) {
        const long i = i4 << 2;
        if (isbf) {
            *(ushort4*)(dst + i) = *(const ushort4*)((const u16*)src + i);
        } else {
            const float4 v = *(const float4*)((const float*)src + i);
            ushort4 o;
            o.x = f2b(v.x); o.y = f2b(v.y); o.z = f2b(v.z); o.w = f2b(v.w);
            *(ushort4*)(dst + i) = o;
        }
    }
}

// ---------------------------------------------------------------------------
// 256x256 MFMA GEMM (NT), BK=32, 4-deep LDS ring: C[m][n]=sum_k A[m][k]*B[n][k]
//   (+bias[n], softsign). M,N mult of 256; K mult of 32 (>=96). bf16, fp32 acc.
// 512 thr = 8 waves (2M x 4N); per-wave 128x64 out = 8x4 frags of 16x16x32.
// LDS 128 KiB = 4 ring buffers x 32 KiB (A 16K + B 16K), K-step 32.
// Per K-tile: 2 phases x 16 MFMA. Prologue stages tiles 0..2; iter t stages
// tile t+3 (4 loads/thread) and does ONE counted s_waitcnt vmcnt(8) at phase B
// (retires tile t+1; tiles t+2,t+3 = 8 loads stay in flight). Prefetch
// distance ~2.5 K-tiles (~1250 cyc) > HBM latency (~900 cyc).
// Ring-write hazard: stage target (t+3)%4 == (t-1)%4; its last reads finished
// before the barrier that precedes the stage (reads feed MFMA before the
// phase-final s_barrier). vmcnt retires in order; gld16 retire => LDS visible.
// LDS swizzle (both-sides): granule (row r, 16B-granule q) stored at
// q^((r>>1)&3); applied on the GLOBAL source k-offset (gld16 dest linear) and
// on the ds_read offset -> consecutive-8-lane b128 groups hit 8 bank-quads.
// ---------------------------------------------------------------------------
template<bool BIAS, bool SOFTSIGN>
__global__ __launch_bounds__(512, 2) void gemm256_nt(
    const u16* __restrict__ A, const u16* __restrict__ B,
    const u16* __restrict__ bias, u16* __restrict__ C,
    int M, int N, int K, int lda, int ldb, int ldc,
    long sA, long sB, long sC)
{
    extern __shared__ char smem[];

    int mt, nt, zt;
    swizzle_tiles(mt, nt, zt);
    const u16* Ab = A + (long)zt * sA + (long)(mt * 256) * lda;
    const u16* Bb = B + (long)zt * sB + (long)(nt * 256) * ldb;
    C += (long)zt * sC;

    const int tid  = threadIdx.x;
    const int lane = tid & 63;
    const int wv   = tid >> 6;          // 0..7
    const int wr   = (wv >> 2) * 128;   // wave row in tile
    const int wc   = (wv & 3) * 64;     // wave col in tile
    const int lm   = lane & 15;
    const int q    = lane >> 4;

    // ---- swizzled read byte-offsets within a 16 KiB [256r][32k] region ----
    int aOff[2][4], bOff[4];
    #pragma unroll
    for (int mh = 0; mh < 2; ++mh)
        #pragma unroll
        for (int i = 0; i < 4; ++i) {
            const int r = wr + mh * 64 + i * 16 + lm;
            aOff[mh][i] = r * 64 + ((q ^ ((r >> 1) & 3)) << 4);
        }
    #pragma unroll
    for (int j = 0; j < 4; ++j) {
        const int r = wc + j * 16 + lm;
        bOff[j] = r * 64 + ((q ^ ((r >> 1) & 3)) << 4);
    }

    // ---- staging: wave w covers rows 32w..32w+31 (2 chunks x 16 rows) ------
    // gld16 dest is linear (base + lane*16); swizzle via pre-permuted GLOBAL
    // k-granule (involution == its own inverse).
    const int rw = lane >> 2, qs = lane & 3;
    const u16* pA[2]; const u16* pB[2];
    int ldsC[2];                       // wave-uniform byte offset within region
    #pragma unroll
    for (int c = 0; c < 2; ++c) {
        const int r = wv * 32 + c * 16 + rw;
        const int kq = (qs ^ ((r >> 1) & 3)) << 3;   // swizzled 8-elem granule
        pA[c] = Ab + (long)r * lda + kq;
        pB[c] = Bb + (long)r * ldb + kq;
        ldsC[c] = wv * 2048 + c * 1024;
    }

    // 4 loads/thread per K-tile, fixed issue order (vmcnt counts on this)
#define STAGE(bufOff, kofs) { \
    gld16(pA[0] + (kofs), (u16*)(smem + (bufOff) + ldsC[0])); \
    gld16(pA[1] + (kofs), (u16*)(smem + (bufOff) + ldsC[1])); \
    gld16(pB[0] + (kofs), (u16*)(smem + (bufOff) + 16384 + ldsC[0])); \
    gld16(pB[1] + (kofs), (u16*)(smem + (bufOff) + 16384 + ldsC[1])); }

#define RDA(mh, bo) { \
    const char* base_ = smem + (bo); \
    a[0] = *(const bf16x8*)(base_ + aOff[mh][0]); \
    a[1] = *(const bf16x8*)(base_ + aOff[mh][1]); \
    a[2] = *(const bf16x8*)(base_ + aOff[mh][2]); \
    a[3] = *(const bf16x8*)(base_ + aOff[mh][3]); }

#define RDB(bo) { \
    const char* base_ = smem + (bo) + 16384; \
    b[0] = *(const bf16x8*)(base_ + bOff[0]); \
    b[1] = *(const bf16x8*)(base_ + bOff[1]); \
    b[2] = *(const bf16x8*)(base_ + bOff[2]); \
    b[3] = *(const bf16x8*)(base_ + bOff[3]); }

#define MMA(mh) do { \
    __builtin_amdgcn_s_setprio(1); \
    acc[(mh)*4+0][0] = __builtin_amdgcn_mfma_f32_16x16x32_bf16(a[0], b[0], acc[(mh)*4+0][0], 0,0,0); \
    acc[(mh)*4+0][1] = __builtin_amdgcn_mfma_f32_16x16x32_bf16(a[0], b[1], acc[(mh)*4+0][1], 0,0,0); \
    acc[(mh)*4+0][2] = __builtin_amdgcn_mfma_f32_16x16x32_bf16(a[0], b[2], acc[(mh)*4+0][2], 0,0,0); \
    acc[(mh)*4+0][3] = __builtin_amdgcn_mfma_f32_16x16x32_bf16(a[0], b[3], acc[(mh)*4+0][3], 0,0,0); \
    acc[(mh)*4+1][0] = __builtin_amdgcn_mfma_f32_16x16x32_bf16(a[1], b[0], acc[(mh)*4+1][0], 0,0,0); \
    acc[(mh)*4+1][1] = __builtin_amdgcn_mfma_f32_16x16x32_bf16(a[1], b[1], acc[(mh)*4+1][1], 0,0,0); \
    acc[(mh)*4+1][2] = __builtin_amdgcn_mfma_f32_16x16x32_bf16(a[1], b[2], acc[(mh)*4+1][2], 0,0,0); \
    acc[(mh)*4+1][3] = __builtin_amdgcn_mfma_f32_16x16x32_bf16(a[1], b[3], acc[(mh)*4+1][3], 0,0,0); \
    acc[(mh)*4+2][0] = __builtin_amdgcn_mfma_f32_16x16x32_bf16(a[2], b[0], acc[(mh)*4+2][0], 0,0,0); \
    acc[(mh)*4+2][1] = __builtin_amdgcn_mfma_f32_16x16x32_bf16(a[2], b[1], acc[(mh)*4+2][1], 0,0,0); \
    acc[(mh)*4+2][2] = __builtin_amdgcn_mfma_f32_16x16x32_bf16(a[2], b[2], acc[(mh)*4+2][2], 0,0,0); \
    acc[(mh)*4+2][3] = __builtin_amdgcn_mfma_f32_16x16x32_bf16(a[2], b[3], acc[(mh)*4+2][3], 0,0,0); \
    acc[(mh)*4+3][0] = __builtin_amdgcn_mfma_f32_16x16x32_bf16(a[3], b[0], acc[(mh)*4+3][0], 0,0,0); \
    acc[(mh)*4+3][1] = __builtin_amdgcn_mfma_f32_16x16x32_bf16(a[3], b[1], acc[(mh)*4+3][1], 0,0,0); \
    acc[(mh)*4+3][2] = __builtin_amdgcn_mfma_f32_16x16x32_bf16(a[3], b[2], acc[(mh)*4+3][2], 0,0,0); \
    acc[(mh)*4+3][3] = __builtin_amdgcn_mfma_f32_16x16x32_bf16(a[3], b[3], acc[(mh)*4+3][3], 0,0,0); \
    __builtin_amdgcn_s_setprio(0); \
} while (0)

#define BAR() __builtin_amdgcn_s_barrier()
#define WAIT_VM8() { asm volatile("s_waitcnt vmcnt(8)" ::: "memory"); \
                     __builtin_amdgcn_sched_barrier(0); }

    f32x4 acc[8][4] = {};
    bf16x8 a[4], b[4];

    const int NT = K >> 5;             // K-steps of 32 (K >= 96 guaranteed)

    // prologue: stage tiles 0,1,2 into ring bufs 0,1,2 (12 loads out)
    STAGE(0, 0);
    STAGE(32768, 32);
    STAGE(65536, 64);
    WAIT_VM8();   // tile 0 resident; tiles 1,2 in flight
    BAR();

    for (int t = 0; t < NT; ++t) {
        const int bo = (t & 3) * 32768;
        const int bn = ((t + 3) & 3) * 32768;
        const int kn = ((t + 3 < NT) ? (t + 3) : (NT - 1)) * 32;  // clamp tail

        // phase A: mh=0 quad over full BK; stage tile t+3
        RDA(0, bo); RDB(bo);
        STAGE(bn, kn);
        BAR(); MMA(0); BAR();
        // phase B: mh=1 quad; retire tile t+1 (leave 8 loads in flight)
        RDA(1, bo);
        WAIT_VM8();
        BAR(); MMA(1); BAR();
    }

#undef STAGE
#undef RDA
#undef RDB
#undef MMA
#undef BAR
#undef WAIT_VM8

    // drain all outstanding prefetches before LDS reuse, then repack + store
    asm volatile("s_waitcnt vmcnt(0)" ::: "memory");
    __builtin_amdgcn_sched_barrier(0);
    __syncthreads();

    float* rep = (float*)smem + wv * (16 * 65);
    const int rr = lane >> 2;
    const int cg = lane & 3;
    const int m0 = mt * 256;
    const int n0 = nt * 256;
    #pragma unroll
    for (int i = 0; i < 8; ++i) {      // row-frag: row = wr + 16*i
        #pragma unroll
        for (int j = 0; j < 4; ++j) {  // col-frag: col = wc + 16*j
            const int col = 16 * j + lm;
            const float bj = BIAS ? b2f(bias[n0 + wc + col]) : 0.0f;
            #pragma unroll
            for (int r = 0; r < 4; ++r) {
                float v = acc[i][j][r] + bj;
                if (SOFTSIGN) v = v / (1.0f + fabsf(v));
                rep[(q * 4 + r) * 65 + col] = v;
            }
        }
        // intra-wave LDS RAW/WAR: wave-lockstep + per-wave buffer
        const float* lr = rep + rr * 65 + cg * 16;
        const float4 f0 = *(const float4*)(lr + 0);
        const float4 f1 = *(const float4*)(lr + 4);
        const float4 f2 = *(const float4*)(lr + 8);
        const float4 f3 = *(const float4*)(lr + 12);
        ushort8v o0, o1;
        o0[0] = f2b(f0.x); o0[1] = f2b(f0.y); o0[2] = f2b(f0.z); o0[3] = f2b(f0.w);
        o0[4] = f2b(f1.x); o0[5] = f2b(f1.y); o0[6] = f2b(f1.z); o0[7] = f2b(f1.w);
        o1[0] = f2b(f2.x); o1[1] = f2b(f2.y); o1[2] = f2b(f2.z); o1[3] = f2b(f2.w);
        o1[4] = f2b(f3.x); o1[5] = f2b(f3.y); o1[6] = f2b(f3.z); o1[7] = f2b(f3.w);
        u16* cp = C + (long)(m0 + wr + 16 * i + rr) * ldc + n0 + wc + cg * 16;
        *(ushort8v*)cp = o0;
        *(ushort8v*)(cp + 8) = o1;
    }
}

// ---------------------------------------------------------------------------
// bf16 tiled transpose: src [R][Cc] -> dst [Cc][R] per batch
// ---------------------------------------------------------------------------
__global__ __launch_bounds__(256) void transpose_bf16(
    const u16* __restrict__ src, u16* __restrict__ dst,
    int R, int Cc, long sS, long sD)
{
    __shared__ u16 t[32][33];
    const int bz = blockIdx.z;
    src += (long)bz * sS;
    dst += (long)bz * sD;
    const int c0 = blockIdx.x * 32;
    const int r0 = blockIdx.y * 32;
    const int lx = threadIdx.x & 31;
    const int ly = threadIdx.x >> 5;   // 0..7
    #pragma unroll
    for (int d = 0; d < 32; d += 8)
        t[ly + d][lx] = src[(long)(r0 + ly + d) * Cc + c0 + lx];
    __syncthreads();
    #pragma unroll
    for (int d = 0; d < 32; d += 8)
        dst[(long)(c0 + ly + d) * R + r0 + lx] = t[lx][ly + d];
}

// ---------------------------------------------------------------------------
// BN stats over (N, L) per channel f (layout (N, FC, Lc)). One block/channel.
// Threads split across n when Lc/4 < 256 so all 256 threads stay active.
// ---------------------------------------------------------------------------
__global__ __launch_bounds__(256) void bn_stats(
    const u16* __restrict__ src, const u16* __restrict__ gamma,
    const u16* __restrict__ beta, float* __restrict__ ss,
    int Lc, int nOuter)
{
    const int f = blockIdx.x;
    const long outerStride = (long)FC * Lc;
    const u16* base = src + (long)f * Lc;

    const int vecs = Lc >> 2;                    // 128 (Lc=512) or 256 (Lc=1024)
    const int tpn  = (vecs < 256) ? vecs : 256;  // threads covering one n-row
    const int nGrp = 256 / tpn;                  // n-rows processed in parallel
    const int sub  = threadIdx.x / tpn;
    const int off4 = (threadIdx.x % tpn) << 2;

    float s1 = 0.f, s2 = 0.f;
    for (int n = sub; n < nOuter; n += nGrp) {
        const u16* p = base + (long)n * outerStride;
        for (int i = off4; i < Lc; i += (tpn << 2)) {
            const ushort4 v = *(const ushort4*)(p + i);
            const float a = b2f(v.x), b = b2f(v.y), c = b2f(v.z), d = b2f(v.w);
            s1 += a + b + c + d;
            s2 += a * a + b * b + c * c + d * d;
        }
    }

    __shared__ float r1[256], r2[256];
    const int tid = threadIdx.x;
    r1[tid] = s1;
    r2[tid] = s2;
    __syncthreads();
    for (int s = 128; s > 0; s >>= 1) {
        if (tid < s) { r1[tid] += r1[tid + s]; r2[tid] += r2[tid + s]; }
        __syncthreads();
    }
    if (tid == 0) {
        const float cnt  = (float)nOuter * (float)Lc;
        const float mean = r1[0] / cnt;
        const float var  = r2[0] / cnt - mean * mean;
        const float rstd = rsqrtf(var + BN_EPS);
        const float sc   = b2f(gamma[f]) * rstd;
        ss[f]      = sc;
        ss[FC + f] = b2f(beta[f]) - mean * sc;
    }
}

// dst = src*scale+shift (+ add); add dtype per addflag, dst dtype per outflag
// Lc is a power of two: channel = (i >> lcShift) & (FC-1)
template<bool ADD>
__global__ __launch_bounds__(256) void bn_apply(
    const u16* __restrict__ src, const void* __restrict__ add,
    const int* __restrict__ addflag,
    const float* __restrict__ ss, void* __restrict__ dst,
    const int* __restrict__ outflag, long total4, int lcShift)
{
    const bool addf32 = ADD && (addflag != nullptr) && (*addflag == 0);
    const bool outf32 = (outflag != nullptr) && (*outflag == 0);
    long i4 = (long)blockIdx.x * blockDim.x + threadIdx.x;
    const long stride = (long)gridDim.x * blockDim.x;
    for (; i4 < total4; i4 += stride) {
        const long i = i4 << 2;
        const int c = (int)((i >> lcShift) & (FC - 1));
        const float sc = ss[c];
        const float sh = ss[FC + c];
        const ushort4 v = *(const ushort4*)(src + i);
        float o0 = fmaf(b2f(v.x), sc, sh);
        float o1 = fmaf(b2f(v.y), sc, sh);
        float o2 = fmaf(b2f(v.z), sc, sh);
        float o3 = fmaf(b2f(v.w), sc, sh);
        if (ADD) {
            if (addf32) {
                const float4 a = *(const float4*)((const float*)add + i);
                o0 += a.x; o1 += a.y; o2 += a.z; o3 += a.w;
            } else {
                const ushort4 a = *(const ushort4*)((const u16*)add + i);
                o0 += b2f(a.x); o1 += b2f(a.y); o2 += b2f(a.z); o3 += b2f(a.w);
            }
        }
        if (outf32) {
            float4 o; o.x = o0; o.y = o1; o.z = o2; o.w = o3;
            *(float4*)((float*)dst + i) = o;
        } else {
            ushort4 o;
            o.x = f2b(o0); o.y = f2b(o1); o.z = f2b(o2); o.w = f2b(o3);
            *(ushort4*)((u16*)dst + i) = o;
        }
    }
}

// dst = a + b + bias[channel], all bf16; channel = (i >> lcShift) & (FC-1)
__global__ __launch_bounds__(256) void add3_bias(
    const u16* __restrict__ a, const u16* __restrict__ b,
    const u16* __restrict__ bias, u16* __restrict__ dst,
    long total4, int lcShift)
{
    long i4 = (long)blockIdx.x * blockDim.x + threadIdx.x;
    const long stride = (long)gridDim.x * blockDim.x;
    for (; i4 < total4; i4 += stride) {
        const long i = i4 << 2;
        const int c = (int)((i >> lcShift) & (FC - 1));
        const float bs = b2f(bias[c]);
        const ushort4 va = *(const ushort4*)(a + i);
        const ushort4 vb = *(const ushort4*)(b + i);
        ushort4 o;
        o.x = f2b(b2f(va.x) + b2f(vb.x) + bs);
        o.y = f2b(b2f(va.y) + b2f(vb.y) + bs);
        o.z = f2b(b2f(va.z) + b2f(vb.z) + bs);
        o.w = f2b(b2f(va.w) + b2f(vb.w) + bs);
        *(ushort4*)(dst + i) = o;
    }
}

extern "C" void kernel_launch(void* const* d_in, const int* in_sizes, int n_in,
                              void* d_out, int out_size, void* d_ws, size_t ws_size,
                              hipStream_t stream)
{
    const size_t MiB = (size_t)1 << 20;
    const long sFH = (long)FC * HH;        // 1,048,576 elems (2 MiB bf16)
    const long sFF = (long)FC * FC;        // 1,048,576
    const long sFD = (long)FC * DD;        //   524,288 (1 MiB)
    const long VE  = (long)NB * FC * HH;   // 33,554,432 (64 MiB)
    const long PE  = (long)NB * FC * DD;   // 16,777,216 (32 MiB)

    const size_t GLDS = 131072;            // 128 KiB dynamic LDS for gemm256
    static bool s_attr = false;
    if (!s_attr) {
        s_attr = true;
        hipFuncSetAttribute(reinterpret_cast<const void*>(&gemm256_nt<true, false>),
                            hipFuncAttributeMaxDynamicSharedMemorySize, (int)GLDS);
        hipFuncSetAttribute(reinterpret_cast<const void*>(&gemm256_nt<false, true>),
                            hipFuncAttributeMaxDynamicSharedMemorySize, (int)GLDS);
        hipFuncSetAttribute(reinterpret_cast<const void*>(&gemm256_nt<false, false>),
                            hipFuncAttributeMaxDynamicSharedMemorySize, (int)GLDS);
    }

    // bf16 param packing offsets
    long off[16];
    long cur = 0;
    for (int i = 1; i < 15; ++i) { off[i] = cur; cur += ((long)in_sizes[i] + 7) & ~7L; }
    const size_t paramBytes = (size_t)cur * 2;

    // adaptive correlation chunk: scratch = cb*6 MiB (VT + W + V2)
    int cb = 16;
    while (cb > 1 &&
           64 * MiB + (size_t)cb * 6 * MiB + paramBytes + 16384 > ws_size)
        cb >>= 1;

    // ---- workspace layout ----
    u16* V   = (u16*)d_ws;                          // 64 MiB: v (N,F,H)
    u16* VT  = (u16*)((char*)d_ws + 64 * MiB);      // cb*2 MiB: v^T chunk
    u16* WW  = VT + (long)cb * sFH;                 // cb*2 MiB: w chunk
    u16* V2  = WW + (long)cb * sFF;                 // cb*2 MiB: v2 chunk
    u16* WC  = V2 + (long)cb * sFH;                 // packed bf16 params
    char* tail = (char*)(WC + cur);
    tail = (char*)(((uintptr_t)tail + 255) & ~(uintptr_t)255);
    float* SS   = (float*)tail;                     // 8 KiB folded BN
    int*   FLAG = (int*)(SS + 2 * FC);
    // d_out (fp32 out => 64 MiB): lower 32 MiB = VX (v3->s->xr), upper = XB
    u16* VX  = (u16*)d_out;
    u16* XB  = (u16*)d_out + PE;                    // x as bf16
    u16* V4  = V;                                   // v4/t (N,F,D) reuses V
    u16* XRT = V + PE;                              // xr^T reuses V upper half

    const dim3 blk(256);
    const dim3 blk512(512);
    const dim3 egrid(4096);

    // 0. detect dtype; convert params + x to bf16
    detect_dtype<<<1, blk, 0, stream>>>((const u32*)d_in[0], FLAG);
    for (int i = 1; i < 15; ++i) {
        const long n4 = (long)in_sizes[i] / 4;
        int g = (int)((n4 + 255) / 256);
        if (g > 1024) g = 1024;
        if (g < 1) g = 1;
        convert_to_bf16<<<dim3(g), blk, 0, stream>>>(d_in[i], WC + off[i], n4, FLAG);
    }
    convert_to_bf16<<<dim3(1024), blk, 0, stream>>>(d_in[0], XB, PE / 4, FLAG);

    const u16* W0c = WC + off[1];
    const u16* b0c = WC + off[2];
    const u16* g0c = WC + off[3];
    const u16* be0c = WC + off[4];
    const u16* W1c = WC + off[5];
    const u16* b1c = WC + off[6];
    const u16* g1c = WC + off[7];
    const u16* be1c = WC + off[8];
    const u16* gfc = WC + off[9];
    const u16* bfc = WC + off[10];
    const u16* Wcc = WC + off[11];
    const u16* bcc = WC + off[12];
    const u16* goc = WC + off[13];
    const u16* boc = WC + off[14];

    // 1. v = x @ W0^T + b0   (M=32768, N=1024, K=512)
    gemm256_nt<true, false><<<dim3(HH / 256, (NB * FC) / 256, 1), blk512, GLDS, stream>>>(
        XB, W0c, b0c, V, NB * FC, HH, DD, DD, DD, HH, 0, 0, 0);

    // 2-3. v = BN0(v)
    bn_stats<<<FC, blk, 0, stream>>>(V, g0c, be0c, SS, HH, NB);
    bn_apply<false><<<egrid, blk, 0, stream>>>(V, nullptr, nullptr, SS, V, nullptr, VE / 4, 10);

    // 4-6 per chunk: vT; w = softsign(v v^T); v2 = w @ v (via vT); v3 = v2 @ W1^T + b1
    for (int bz0 = 0; bz0 < NB; bz0 += cb) {
        const int c = (NB - bz0 < cb) ? (NB - bz0) : cb;
        transpose_bf16<<<dim3(HH / 32, FC / 32, c), blk, 0, stream>>>(
            V + bz0 * sFH, VT, FC, HH, sFH, sFH);
        gemm256_nt<false, true><<<dim3(FC / 256, FC / 256, c), blk512, GLDS, stream>>>(
            V + bz0 * sFH, V + bz0 * sFH, nullptr, WW,
            FC, FC, HH, HH, HH, FC, sFH, sFH, sFF);
        gemm256_nt<false, false><<<dim3(HH / 256, FC / 256, c), blk512, GLDS, stream>>>(
            WW, VT, nullptr, V2,
            FC, HH, FC, FC, FC, HH, sFF, sFH, sFH);
        gemm256_nt<true, false><<<dim3(DD / 256, (c * FC) / 256, 1), blk512, GLDS, stream>>>(
            V2, W1c, b1c, VX + bz0 * sFD,
            c * FC, DD, HH, HH, HH, DD, 0, 0, 0);
    }

    // 7-8. s = BN1(v3) + x   (in place in VX; x from bf16 copy XB)
    bn_stats<<<FC, blk, 0, stream>>>(VX, g1c, be1c, SS, DD, NB);
    bn_apply<true><<<egrid, blk, 0, stream>>>(VX, XB, nullptr, SS, VX, nullptr, PE / 4, 9);

    // 9-10. xr = BNf(s)      (in place in VX)
    bn_stats<<<FC, blk, 0, stream>>>(VX, gfc, bfc, SS, DD, NB);
    bn_apply<false><<<egrid, blk, 0, stream>>>(VX, nullptr, nullptr, SS, VX, nullptr, PE / 4, 9);

    // 11. xr^T, then v4 = Wc @ xr  (NT via xr^T) -> V4
    transpose_bf16<<<dim3(DD / 32, FC / 32, NB), blk, 0, stream>>>(
        VX, XRT, FC, DD, sFD, sFD);
    gemm256_nt<false, false><<<dim3(DD / 256, FC / 256, NB), blk512, GLDS, stream>>>(
        Wcc, XRT, nullptr, V4, FC, DD, FC, FC, FC, DD, 0, sFD, sFD);

    // 12. t = v4 + bc + xr  (in place V4)
    add3_bias<<<egrid, blk, 0, stream>>>(V4, VX, bcc, V4, PE / 4, 9);

    // 13-14. out = BNo(t); out dtype per FLAG
    bn_stats<<<FC, blk, 0, stream>>>(V4, goc, boc, SS, DD, NB);
    bn_apply<false><<<egrid, blk, 0, stream>>>(V4, nullptr, nullptr, SS, d_out, FLAG, PE / 4, 9);
}

// Round 3
// 671.356 us; speedup vs baseline: 1.1679x; 1.0282x over previous
//
#include <hip/hip_runtime.h>
#include <stdint.h>

#define NB 32
#define FC 1024
#define DD 512
#define HH 1024
#define BN_EPS 1e-5f

typedef unsigned short u16;
typedef unsigned int u32;
typedef __attribute__((ext_vector_type(8))) short bf16x8;   // 8 bf16 = 4 VGPRs
typedef __attribute__((ext_vector_type(4))) float f32x4;
typedef __attribute__((ext_vector_type(8))) unsigned short ushort8v;

#define AS1 __attribute__((address_space(1)))
#define AS3 __attribute__((address_space(3)))

__device__ __forceinline__ float b2f(u16 u) {
    union { u32 i; float f; } v;
    v.i = ((u32)u) << 16;
    return v.f;
}
__device__ __forceinline__ u16 f2b(float f) {
    union { float f; u32 i; } v;
    v.f = f;
    const u32 b = v.i;
    return (u16)((b + 0x7FFFu + ((b >> 16) & 1u)) >> 16);
}

// async global->LDS, 16B per lane; lds dest must be wave-uniform base
__device__ __forceinline__ void gld16(const u16* g, u16* l) {
    __builtin_amdgcn_global_load_lds((const AS1 u32*)g, (AS3 u32*)l, 16, 0, 0);
}

// XCD-aware tile swizzle: lin%8 = XCD slab over (m,z); each XCD iterates n
// fastest within its slab -> A-tile reuse lands in one XCD's L2.
__device__ __forceinline__ void swizzle_tiles(int& mt, int& nt, int& zt) {
    const int gx = gridDim.x, gy = gridDim.y, gz = gridDim.z;
    const int mzTot = gy * gz;
    if ((mzTot & 7) != 0) { nt = blockIdx.x; mt = blockIdx.y; zt = blockIdx.z; return; }
    long lin = ((long)blockIdx.z * gy + blockIdx.y) * gx + blockIdx.x;
    const int slab = mzTot >> 3;
    const int xcd = (int)(lin & 7);
    const long idx = lin >> 3;
    nt = (int)(idx % gx);
    const int mz = (int)(idx / gx) + xcd * slab;
    mt = mz % gy;
    zt = mz / gy;
}

// ---------------------------------------------------------------------------
// Dtype detection: flag=1 if x is bf16 pairs, 0 if fp32.
// ---------------------------------------------------------------------------
__global__ __launch_bounds__(256) void detect_dtype(
    const u32* __restrict__ x, int* __restrict__ flag)
{
    __shared__ int cnt[256];
    int c = 0;
    for (int i = threadIdx.x; i < 4096; i += 256) {
        const u32 lo = x[i] & 0xFFFFu;
        const u32 e = (lo >> 7) & 0xFFu;
        if (e >= 0x68u && e <= 0x85u) c++;
    }
    cnt[threadIdx.x] = c;
    __syncthreads();
    for (int s = 128; s > 0; s >>= 1) {
        if (threadIdx.x < (unsigned)s) cnt[threadIdx.x] += cnt[threadIdx.x + s];
        __syncthreads();
    }
    if (threadIdx.x == 0) flag[0] = (cnt[0] > 2048) ? 1 : 0;
}

__global__ __launch_bounds__(256) void convert_to_bf16(
    const void* __restrict__ src, u16* __restrict__ dst, long n4,
    const int* __restrict__ flag)
{
    const bool isbf = (*flag != 0);
    long i4 = (long)blockIdx.x * blockDim.x + threadIdx.x;
    const long stride = (long)gridDim.x * blockDim.x;
    for (; i4 < n4; i4 += stride) {
        const long i = i4 << 2;
        if (isbf) {
            *(ushort4*)(dst + i) = *(const ushort4*)((const u16*)src + i);
        } else {
            const float4 v = *(const float4*)((const float*)src + i);
            ushort4 o;
            o.x = f2b(v.x); o.y = f2b(v.y); o.z = f2b(v.z); o.w = f2b(v.w);
            *(ushort4*)(dst + i) = o;
        }
    }
}

// ---------------------------------------------------------------------------
// 128x256 MFMA GEMM (NT), BK=32, double-buffered: C[m][n]=sum_k A[m][k]*B[n][k]
//   (+bias[n], softsign). M mult 128, N mult 256, K mult 32. bf16, fp32 acc.
// 512 thr = 8 waves (2M x 4N); per-wave 64x64 out = 4x4 frags of 16x16x32.
// acc = 64 regs/wave -> total ~120 unified regs -> 4 waves/SIMD; LDS 48 KiB
// (2 bufs x [A 8K + B 16K]) -> 2 BLOCKS/CU co-resident (96 KiB of 160).
// Mechanism: cross-block TLP fills lgkm/vmcnt/barrier gaps (m97/m114 regime)
// instead of intra-block scheduling. One __syncthreads per K-tile; stage
// issued BEFORE reads (minimum-2-phase recipe); no asm in the loop.
// LDS swizzle (both-sides): granule (row r, 16B-granule q) stored at
// q^((r>>1)&3); applied on the GLOBAL source k-offset (gld16 dest linear) and
// on the ds_read offset -> conflict-free-ish b128 reads (verified R1/R2).
// ---------------------------------------------------------------------------
template<bool BIAS, bool SOFTSIGN>
__global__ __launch_bounds__(512, 4) void gemm128x256_nt(
    const u16* __restrict__ A, const u16* __restrict__ B,
    const u16* __restrict__ bias, u16* __restrict__ C,
    int M, int N, int K, int lda, int ldb, int ldc,
    long sA, long sB, long sC)
{
    extern __shared__ char smem[];

    int mt, nt, zt;
    swizzle_tiles(mt, nt, zt);
    const u16* Ab = A + (long)zt * sA + (long)(mt * 128) * lda;
    const u16* Bb = B + (long)zt * sB + (long)(nt * 256) * ldb;
    C += (long)zt * sC;

    const int tid  = threadIdx.x;
    const int lane = tid & 63;
    const int wv   = tid >> 6;          // 0..7
    const int wrr  = (wv >> 2) * 64;    // wave row offset in tile (0/64)
    const int wc   = (wv & 3) * 64;     // wave col offset in tile
    const int lm   = lane & 15;
    const int q    = lane >> 4;         // k-granule 0..3

    // ---- swizzled read byte-offsets (A region [128][32], B region [256][32])
    int aOff[4], bOff[4];
    #pragma unroll
    for (int i = 0; i < 4; ++i) {
        const int r = wrr + i * 16 + lm;
        aOff[i] = r * 64 + ((q ^ ((r >> 1) & 3)) << 4);
    }
    #pragma unroll
    for (int j = 0; j < 4; ++j) {
        const int r = wc + j * 16 + lm;
        bOff[j] = r * 64 + ((q ^ ((r >> 1) & 3)) << 4);
    }

    // ---- staging: 3 gld16/thread (A: rows wv*16+.., B: rows wv*32+..) ------
    // gld16 dest linear (base + lane*16); swizzle via pre-permuted GLOBAL
    // k-granule (involution == its own inverse).
    const int rw = lane >> 2, qs = lane & 3;
    const int rA  = wv * 16 + rw;
    const int rB0 = wv * 32 + rw;
    const int rB1 = wv * 32 + 16 + rw;
    const u16* pA  = Ab + (long)rA  * lda + ((qs ^ ((rA  >> 1) & 3)) << 3);
    const u16* pB0 = Bb + (long)rB0 * ldb + ((qs ^ ((rB0 >> 1) & 3)) << 3);
    const u16* pB1 = Bb + (long)rB1 * ldb + ((qs ^ ((rB1 >> 1) & 3)) << 3);
    const int ldsA  = wv * 1024;
    const int ldsB0 = wv * 2048;
    const int ldsB1 = wv * 2048 + 1024;

#define STAGE(bufOff, kofs) { \
    gld16(pA  + (kofs), (u16*)(smem + (bufOff) + ldsA)); \
    gld16(pB0 + (kofs), (u16*)(smem + (bufOff) + 8192 + ldsB0)); \
    gld16(pB1 + (kofs), (u16*)(smem + (bufOff) + 8192 + ldsB1)); }

    f32x4 acc[4][4] = {};

    const int NT = K >> 5;             // K-steps of 32

    STAGE(0, 0);
    __syncthreads();                   // tile 0 resident (vmcnt+lgkm drained)

    for (int t = 0; t < NT; ++t) {
        const int bo = (t & 1) * 24576;
        const int bn = ((t + 1) & 1) * 24576;
        if (t + 1 < NT) STAGE(bn, (t + 1) * 32);

        bf16x8 a[4], b[4];
        const char* baseA = smem + bo;
        const char* baseB = smem + bo + 8192;
        #pragma unroll
        for (int i = 0; i < 4; ++i) a[i] = *(const bf16x8*)(baseA + aOff[i]);
        #pragma unroll
        for (int j = 0; j < 4; ++j) b[j] = *(const bf16x8*)(baseB + bOff[j]);

        #pragma unroll
        for (int i = 0; i < 4; ++i)
            #pragma unroll
            for (int j = 0; j < 4; ++j)
                acc[i][j] = __builtin_amdgcn_mfma_f32_16x16x32_bf16(
                    a[i], b[j], acc[i][j], 0, 0, 0);

        __syncthreads();               // reads done + next tile resident
    }

#undef STAGE

    // epilogue: per-wave LDS repack (16x65 fp32 each), coalesced bf16 stores
    float* rep = (float*)smem + wv * (16 * 65);
    const int rr = lane >> 2;
    const int cg = lane & 3;
    const int m0 = mt * 128;
    const int n0 = nt * 256;
    #pragma unroll
    for (int i = 0; i < 4; ++i) {      // row-frag: row = wrr + 16*i
        #pragma unroll
        for (int j = 0; j < 4; ++j) {  // col-frag: col = wc + 16*j
            const int col = 16 * j + lm;
            const float bj = BIAS ? b2f(bias[n0 + wc + col]) : 0.0f;
            #pragma unroll
            for (int r = 0; r < 4; ++r) {
                float v = acc[i][j][r] + bj;
                if (SOFTSIGN) v = v / (1.0f + fabsf(v));
                rep[(q * 4 + r) * 65 + col] = v;
            }
        }
        // intra-wave LDS RAW/WAR: wave-lockstep + per-wave buffer
        const float* lr = rep + rr * 65 + cg * 16;
        const float4 f0 = *(const float4*)(lr + 0);
        const float4 f1 = *(const float4*)(lr + 4);
        const float4 f2 = *(const float4*)(lr + 8);
        const float4 f3 = *(const float4*)(lr + 12);
        ushort8v o0, o1;
        o0[0] = f2b(f0.x); o0[1] = f2b(f0.y); o0[2] = f2b(f0.z); o0[3] = f2b(f0.w);
        o0[4] = f2b(f1.x); o0[5] = f2b(f1.y); o0[6] = f2b(f1.z); o0[7] = f2b(f1.w);
        o1[0] = f2b(f2.x); o1[1] = f2b(f2.y); o1[2] = f2b(f2.z); o1[3] = f2b(f2.w);
        o1[4] = f2b(f3.x); o1[5] = f2b(f3.y); o1[6] = f2b(f3.z); o1[7] = f2b(f3.w);
        u16* cp = C + (long)(m0 + wrr + 16 * i + rr) * ldc + n0 + wc + cg * 16;
        *(ushort8v*)cp = o0;
        *(ushort8v*)(cp + 8) = o1;
    }
}

// ---------------------------------------------------------------------------
// bf16 tiled transpose: src [R][Cc] -> dst [Cc][R] per batch
// ---------------------------------------------------------------------------
__global__ __launch_bounds__(256) void transpose_bf16(
    const u16* __restrict__ src, u16* __restrict__ dst,
    int R, int Cc, long sS, long sD)
{
    __shared__ u16 t[32][33];
    const int bz = blockIdx.z;
    src += (long)bz * sS;
    dst += (long)bz * sD;
    const int c0 = blockIdx.x * 32;
    const int r0 = blockIdx.y * 32;
    const int lx = threadIdx.x & 31;
    const int ly = threadIdx.x >> 5;   // 0..7
    #pragma unroll
    for (int d = 0; d < 32; d += 8)
        t[ly + d][lx] = src[(long)(r0 + ly + d) * Cc + c0 + lx];
    __syncthreads();
    #pragma unroll
    for (int d = 0; d < 32; d += 8)
        dst[(long)(c0 + ly + d) * R + r0 + lx] = t[lx][ly + d];
}

// ---------------------------------------------------------------------------
// BN stats over (N, L) per channel f (layout (N, FC, Lc)). One block/channel.
// Threads split across n when Lc/4 < 256 so all 256 threads stay active.
// ---------------------------------------------------------------------------
__global__ __launch_bounds__(256) void bn_stats(
    const u16* __restrict__ src, const u16* __restrict__ gamma,
    const u16* __restrict__ beta, float* __restrict__ ss,
    int Lc, int nOuter)
{
    const int f = blockIdx.x;
    const long outerStride = (long)FC * Lc;
    const u16* base = src + (long)f * Lc;

    const int vecs = Lc >> 2;                    // 128 (Lc=512) or 256 (Lc=1024)
    const int tpn  = (vecs < 256) ? vecs : 256;  // threads covering one n-row
    const int nGrp = 256 / tpn;                  // n-rows processed in parallel
    const int sub  = threadIdx.x / tpn;
    const int off4 = (threadIdx.x % tpn) << 2;

    float s1 = 0.f, s2 = 0.f;
    for (int n = sub; n < nOuter; n += nGrp) {
        const u16* p = base + (long)n * outerStride;
        for (int i = off4; i < Lc; i += (tpn << 2)) {
            const ushort4 v = *(const ushort4*)(p + i);
            const float a = b2f(v.x), b = b2f(v.y), c = b2f(v.z), d = b2f(v.w);
            s1 += a + b + c + d;
            s2 += a * a + b * b + c * c + d * d;
        }
    }

    __shared__ float r1[256], r2[256];
    const int tid = threadIdx.x;
    r1[tid] = s1;
    r2[tid] = s2;
    __syncthreads();
    for (int s = 128; s > 0; s >>= 1) {
        if (tid < s) { r1[tid] += r1[tid + s]; r2[tid] += r2[tid + s]; }
        __syncthreads();
    }
    if (tid == 0) {
        const float cnt  = (float)nOuter * (float)Lc;
        const float mean = r1[0] / cnt;
        const float var  = r2[0] / cnt - mean * mean;
        const float rstd = rsqrtf(var + BN_EPS);
        const float sc   = b2f(gamma[f]) * rstd;
        ss[f]      = sc;
        ss[FC + f] = b2f(beta[f]) - mean * sc;
    }
}

// dst = src*scale+shift (+ add); add dtype per addflag, dst dtype per outflag
// Lc is a power of two: channel = (i >> lcShift) & (FC-1)
template<bool ADD>
__global__ __launch_bounds__(256) void bn_apply(
    const u16* __restrict__ src, const void* __restrict__ add,
    const int* __restrict__ addflag,
    const float* __restrict__ ss, void* __restrict__ dst,
    const int* __restrict__ outflag, long total4, int lcShift)
{
    const bool addf32 = ADD && (addflag != nullptr) && (*addflag == 0);
    const bool outf32 = (outflag != nullptr) && (*outflag == 0);
    long i4 = (long)blockIdx.x * blockDim.x + threadIdx.x;
    const long stride = (long)gridDim.x * blockDim.x;
    for (; i4 < total4; i4 += stride) {
        const long i = i4 << 2;
        const int c = (int)((i >> lcShift) & (FC - 1));
        const float sc = ss[c];
        const float sh = ss[FC + c];
        const ushort4 v = *(const ushort4*)(src + i);
        float o0 = fmaf(b2f(v.x), sc, sh);
        float o1 = fmaf(b2f(v.y), sc, sh);
        float o2 = fmaf(b2f(v.z), sc, sh);
        float o3 = fmaf(b2f(v.w), sc, sh);
        if (ADD) {
            if (addf32) {
                const float4 a = *(const float4*)((const float*)add + i);
                o0 += a.x; o1 += a.y; o2 += a.z; o3 += a.w;
            } else {
                const ushort4 a = *(const ushort4*)((const u16*)add + i);
                o0 += b2f(a.x); o1 += b2f(a.y); o2 += b2f(a.z); o3 += b2f(a.w);
            }
        }
        if (outf32) {
            float4 o; o.x = o0; o.y = o1; o.z = o2; o.w = o3;
            *(float4*)((float*)dst + i) = o;
        } else {
            ushort4 o;
            o.x = f2b(o0); o.y = f2b(o1); o.z = f2b(o2); o.w = f2b(o3);
            *(ushort4*)((u16*)dst + i) = o;
        }
    }
}

// dst = a + b + bias[channel], all bf16; channel = (i >> lcShift) & (FC-1)
__global__ __launch_bounds__(256) void add3_bias(
    const u16* __restrict__ a, const u16* __restrict__ b,
    const u16* __restrict__ bias, u16* __restrict__ dst,
    long total4, int lcShift)
{
    long i4 = (long)blockIdx.x * blockDim.x + threadIdx.x;
    const long stride = (long)gridDim.x * blockDim.x;
    for (; i4 < total4; i4 += stride) {
        const long i = i4 << 2;
        const int c = (int)((i >> lcShift) & (FC - 1));
        const float bs = b2f(bias[c]);
        const ushort4 va = *(const ushort4*)(a + i);
        const ushort4 vb = *(const ushort4*)(b + i);
        ushort4 o;
        o.x = f2b(b2f(va.x) + b2f(vb.x) + bs);
        o.y = f2b(b2f(va.y) + b2f(vb.y) + bs);
        o.z = f2b(b2f(va.z) + b2f(vb.z) + bs);
        o.w = f2b(b2f(va.w) + b2f(vb.w) + bs);
        *(ushort4*)(dst + i) = o;
    }
}

extern "C" void kernel_launch(void* const* d_in, const int* in_sizes, int n_in,
                              void* d_out, int out_size, void* d_ws, size_t ws_size,
                              hipStream_t stream)
{
    const size_t MiB = (size_t)1 << 20;
    const long sFH = (long)FC * HH;        // 1,048,576 elems (2 MiB bf16)
    const long sFF = (long)FC * FC;        // 1,048,576
    const long sFD = (long)FC * DD;        //   524,288 (1 MiB)
    const long VE  = (long)NB * FC * HH;   // 33,554,432 (64 MiB)
    const long PE  = (long)NB * FC * DD;   // 16,777,216 (32 MiB)

    const size_t GLDS = 49152;             // 48 KiB dynamic LDS -> 2 blocks/CU
    static bool s_attr = false;
    if (!s_attr) {
        s_attr = true;
        hipFuncSetAttribute(reinterpret_cast<const void*>(&gemm128x256_nt<true, false>),
                            hipFuncAttributeMaxDynamicSharedMemorySize, (int)GLDS);
        hipFuncSetAttribute(reinterpret_cast<const void*>(&gemm128x256_nt<false, true>),
                            hipFuncAttributeMaxDynamicSharedMemorySize, (int)GLDS);
        hipFuncSetAttribute(reinterpret_cast<const void*>(&gemm128x256_nt<false, false>),
                            hipFuncAttributeMaxDynamicSharedMemorySize, (int)GLDS);
    }

    // bf16 param packing offsets
    long off[16];
    long cur = 0;
    for (int i = 1; i < 15; ++i) { off[i] = cur; cur += ((long)in_sizes[i] + 7) & ~7L; }
    const size_t paramBytes = (size_t)cur * 2;

    // adaptive correlation chunk: scratch = cb*6 MiB (VT + W + V2)
    int cb = 32;
    while (cb > 1 &&
           64 * MiB + (size_t)cb * 6 * MiB + paramBytes + 16384 > ws_size)
        cb >>= 1;

    // ---- workspace layout ----
    u16* V   = (u16*)d_ws;                          // 64 MiB: v (N,F,H)
    u16* VT  = (u16*)((char*)d_ws + 64 * MiB);      // cb*2 MiB: v^T chunk
    u16* WW  = VT + (long)cb * sFH;                 // cb*2 MiB: w chunk
    u16* V2  = WW + (long)cb * sFF;                 // cb*2 MiB: v2 chunk
    u16* WC  = V2 + (long)cb * sFH;                 // packed bf16 params
    char* tail = (char*)(WC + cur);
    tail = (char*)(((uintptr_t)tail + 255) & ~(uintptr_t)255);
    float* SS   = (float*)tail;                     // 8 KiB folded BN
    int*   FLAG = (int*)(SS + 2 * FC);
    // d_out (fp32 out => 64 MiB): lower 32 MiB = VX (v3->s->xr), upper = XB
    u16* VX  = (u16*)d_out;
    u16* XB  = (u16*)d_out + PE;                    // x as bf16
    u16* V4  = V;                                   // v4/t (N,F,D) reuses V
    u16* XRT = V + PE;                              // xr^T reuses V upper half

    const dim3 blk(256);
    const dim3 blk512(512);
    const dim3 egrid(4096);

    // 0. detect dtype; convert params + x to bf16
    detect_dtype<<<1, blk, 0, stream>>>((const u32*)d_in[0], FLAG);
    for (int i = 1; i < 15; ++i) {
        const long n4 = (long)in_sizes[i] / 4;
        int g = (int)((n4 + 255) / 256);
        if (g > 1024) g = 1024;
        if (g < 1) g = 1;
        convert_to_bf16<<<dim3(g), blk, 0, stream>>>(d_in[i], WC + off[i], n4, FLAG);
    }
    convert_to_bf16<<<dim3(1024), blk, 0, stream>>>(d_in[0], XB, PE / 4, FLAG);

    const u16* W0c = WC + off[1];
    const u16* b0c = WC + off[2];
    const u16* g0c = WC + off[3];
    const u16* be0c = WC + off[4];
    const u16* W1c = WC + off[5];
    const u16* b1c = WC + off[6];
    const u16* g1c = WC + off[7];
    const u16* be1c = WC + off[8];
    const u16* gfc = WC + off[9];
    const u16* bfc = WC + off[10];
    const u16* Wcc = WC + off[11];
    const u16* bcc = WC + off[12];
    const u16* goc = WC + off[13];
    const u16* boc = WC + off[14];

    // 1. v = x @ W0^T + b0   (M=32768, N=1024, K=512)
    gemm128x256_nt<true, false><<<dim3(HH / 256, (NB * FC) / 128, 1), blk512, GLDS, stream>>>(
        XB, W0c, b0c, V, NB * FC, HH, DD, DD, DD, HH, 0, 0, 0);

    // 2-3. v = BN0(v)
    bn_stats<<<FC, blk, 0, stream>>>(V, g0c, be0c, SS, HH, NB);
    bn_apply<false><<<egrid, blk, 0, stream>>>(V, nullptr, nullptr, SS, V, nullptr, VE / 4, 10);

    // 4-6 per chunk: vT; w = softsign(v v^T); v2 = w @ v (via vT); v3 = v2 @ W1^T + b1
    for (int bz0 = 0; bz0 < NB; bz0 += cb) {
        const int c = (NB - bz0 < cb) ? (NB - bz0) : cb;
        transpose_bf16<<<dim3(HH / 32, FC / 32, c), blk, 0, stream>>>(
            V + bz0 * sFH, VT, FC, HH, sFH, sFH);
        gemm128x256_nt<false, true><<<dim3(FC / 256, FC / 128, c), blk512, GLDS, stream>>>(
            V + bz0 * sFH, V + bz0 * sFH, nullptr, WW,
            FC, FC, HH, HH, HH, FC, sFH, sFH, sFF);
        gemm128x256_nt<false, false><<<dim3(HH / 256, FC / 128, c), blk512, GLDS, stream>>>(
            WW, VT, nullptr, V2,
            FC, HH, FC, FC, FC, HH, sFF, sFH, sFH);
        gemm128x256_nt<true, false><<<dim3(DD / 256, (c * FC) / 128, 1), blk512, GLDS, stream>>>(
            V2, W1c, b1c, VX + bz0 * sFD,
            c * FC, DD, HH, HH, HH, DD, 0, 0, 0);
    }

    // 7-8. s = BN1(v3) + x   (in place in VX; x from bf16 copy XB)
    bn_stats<<<FC, blk, 0, stream>>>(VX, g1c, be1c, SS, DD, NB);
    bn_apply<true><<<egrid, blk, 0, stream>>>(VX, XB, nullptr, SS, VX, nullptr, PE / 4, 9);

    // 9-10. xr = BNf(s)      (in place in VX)
    bn_stats<<<FC, blk, 0, stream>>>(VX, gfc, bfc, SS, DD, NB);
    bn_apply<false><<<egrid, blk, 0, stream>>>(VX, nullptr, nullptr, SS, VX, nullptr, PE / 4, 9);

    // 11. xr^T, then v4 = Wc @ xr  (NT via xr^T) -> V4
    transpose_bf16<<<dim3(DD / 32, FC / 32, NB), blk, 0, stream>>>(
        VX, XRT, FC, DD, sFD, sFD);
    gemm128x256_nt<false, false><<<dim3(DD / 256, FC / 128, NB), blk512, GLDS, stream>>>(
        Wcc, XRT, nullptr, V4, FC, DD, FC, FC, FC, DD, 0, sFD, sFD);

    // 12. t = v4 + bc + xr  (in place V4)
    add3_bias<<<egrid, blk, 0, stream>>>(V4, VX, bcc, V4, PE / 4, 9);

    // 13-14. out = BNo(t); out dtype per FLAG
    bn_stats<<<FC, blk, 0, stream>>>(V4, goc, boc, SS, DD, NB);
    bn_apply<false><<<egrid, blk, 0, stream>>>(V4, nullptr, nullptr, SS, d_out, FLAG, PE / 4, 9);
}

// Round 4
// 609.900 us; speedup vs baseline: 1.2856x; 1.1008x over previous
//
#include <hip/hip_runtime.h>
#include <stdint.h>

#define NB 32
#define FC 1024
#define DD 512
#define HH 1024
#define BN_EPS 1e-5f

typedef unsigned short u16;
typedef unsigned int u32;
typedef __attribute__((ext_vector_type(8))) short bf16x8;   // 8 bf16 = 4 VGPRs
typedef __attribute__((ext_vector_type(4))) float f32x4;
typedef __attribute__((ext_vector_type(8))) unsigned short ushort8v;

#define AS1 __attribute__((address_space(1)))
#define AS3 __attribute__((address_space(3)))

__device__ __forceinline__ float b2f(u16 u) {
    union { u32 i; float f; } v;
    v.i = ((u32)u) << 16;
    return v.f;
}
__device__ __forceinline__ u16 f2b(float f) {
    union { float f; u32 i; } v;
    v.f = f;
    const u32 b = v.i;
    return (u16)((b + 0x7FFFu + ((b >> 16) & 1u)) >> 16);
}

// async global->LDS, 16B per lane; lds dest must be wave-uniform base
__device__ __forceinline__ void gld16(const u16* g, u16* l) {
    __builtin_amdgcn_global_load_lds((const AS1 u32*)g, (AS3 u32*)l, 16, 0, 0);
}

// XCD-aware tile swizzle: lin%8 = XCD slab over (m,z); each XCD iterates n
// fastest within its slab -> A-tile reuse lands in one XCD's L2.
__device__ __forceinline__ void swizzle_tiles(int& mt, int& nt, int& zt) {
    const int gx = gridDim.x, gy = gridDim.y, gz = gridDim.z;
    const int mzTot = gy * gz;
    if ((mzTot & 7) != 0) { nt = blockIdx.x; mt = blockIdx.y; zt = blockIdx.z; return; }
    long lin = ((long)blockIdx.z * gy + blockIdx.y) * gx + blockIdx.x;
    const int slab = mzTot >> 3;
    const int xcd = (int)(lin & 7);
    const long idx = lin >> 3;
    nt = (int)(idx % gx);
    const int mz = (int)(idx / gx) + xcd * slab;
    mt = mz % gy;
    zt = mz / gy;
}

// ---------------------------------------------------------------------------
// Dtype detection: flag=1 if x is bf16 pairs, 0 if fp32.
// ---------------------------------------------------------------------------
__global__ __launch_bounds__(256) void detect_dtype(
    const u32* __restrict__ x, int* __restrict__ flag)
{
    __shared__ int cnt[256];
    int c = 0;
    for (int i = threadIdx.x; i < 4096; i += 256) {
        const u32 lo = x[i] & 0xFFFFu;
        const u32 e = (lo >> 7) & 0xFFu;
        if (e >= 0x68u && e <= 0x85u) c++;
    }
    cnt[threadIdx.x] = c;
    __syncthreads();
    for (int s = 128; s > 0; s >>= 1) {
        if (threadIdx.x < (unsigned)s) cnt[threadIdx.x] += cnt[threadIdx.x + s];
        __syncthreads();
    }
    if (threadIdx.x == 0) flag[0] = (cnt[0] > 2048) ? 1 : 0;
}

__global__ __launch_bounds__(256) void zero_partials(float* __restrict__ sp) {
    sp[blockIdx.x * 256 + threadIdx.x] = 0.0f;
}

// fold (sum, sumsq) partials -> (scale, shift)
__global__ __launch_bounds__(256) void fold_bn(
    const float* __restrict__ sp, const u16* __restrict__ gamma,
    const u16* __restrict__ beta, float* __restrict__ ssf, float invCnt)
{
    const int f = blockIdx.x * 256 + threadIdx.x;
    if (f < FC) {
        const float mean = sp[f] * invCnt;
        const float var  = sp[FC + f] * invCnt - mean * mean;
        const float rstd = rsqrtf(var + BN_EPS);
        const float sc   = b2f(gamma[f]) * rstd;
        ssf[f]      = sc;
        ssf[FC + f] = b2f(beta[f]) - mean * sc;
    }
}

__global__ __launch_bounds__(256) void convert_to_bf16(
    const void* __restrict__ src, u16* __restrict__ dst, long n4,
    const int* __restrict__ flag)
{
    const bool isbf = (*flag != 0);
    long i4 = (long)blockIdx.x * blockDim.x + threadIdx.x;
    const long stride = (long)gridDim.x * blockDim.x;
    for (; i4 < n4; i4 += stride) {
        const long i = i4 << 2;
        if (isbf) {
            *(ushort4*)(dst + i) = *(const ushort4*)((const u16*)src + i);
        } else {
            const float4 v = *(const float4*)((const float*)src + i);
            ushort4 o;
            o.x = f2b(v.x); o.y = f2b(v.y); o.z = f2b(v.z); o.w = f2b(v.w);
            *(ushort4*)(dst + i) = o;
        }
    }
}

// all 14 params in one launch (saves ~13 tiny dispatches)
struct ConvArgs { const void* src[14]; long off[14]; long n4[14]; };
__global__ __launch_bounds__(256) void convert_params(
    ConvArgs a, u16* __restrict__ dst, const int* __restrict__ flag)
{
    const bool isbf = (*flag != 0);
    const long stride = (long)gridDim.x * blockDim.x;
    for (int s = 0; s < 14; ++s) {
        const long n4 = a.n4[s];
        u16* d = dst + a.off[s];
        const void* sp = a.src[s];
        for (long i4 = (long)blockIdx.x * blockDim.x + threadIdx.x; i4 < n4;
             i4 += stride) {
            const long i = i4 << 2;
            if (isbf) {
                *(ushort4*)(d + i) = *(const ushort4*)((const u16*)sp + i);
            } else {
                const float4 v = *(const float4*)((const float*)sp + i);
                ushort4 o;
                o.x = f2b(v.x); o.y = f2b(v.y); o.z = f2b(v.z); o.w = f2b(v.w);
                *(ushort4*)(d + i) = o;
            }
        }
    }
}

// ---------------------------------------------------------------------------
// 128x256 MFMA GEMM (NT), BK=32, double-buffered (R3 structure, best measured).
// New: STATS fuses per-channel (sum,sumsq) accumulation into the epilogue
// (channel = out-row & (FC-1)); RESID fuses "+resid[row][col]" (resid has C's
// strides) before stats/store. Stats: per-lane 16-col partial, shfl-reduce
// over the 4 col-group lanes, one atomicAdd pair per row (16/wave/iter).
// ---------------------------------------------------------------------------
template<bool BIAS, bool SOFTSIGN, bool STATS, bool RESID>
__global__ __launch_bounds__(512, 4) void gemm128x256_nt(
    const u16* __restrict__ A, const u16* __restrict__ B,
    const u16* __restrict__ bias, const u16* __restrict__ resid,
    u16* __restrict__ C, float* __restrict__ sp,
    int M, int N, int K, int lda, int ldb, int ldc,
    long sA, long sB, long sC)
{
    extern __shared__ char smem[];

    int mt, nt, zt;
    swizzle_tiles(mt, nt, zt);
    const u16* Ab = A + (long)zt * sA + (long)(mt * 128) * lda;
    const u16* Bb = B + (long)zt * sB + (long)(nt * 256) * ldb;
    C += (long)zt * sC;
    const u16* RP = RESID ? (resid + (long)zt * sC) : nullptr;

    const int tid  = threadIdx.x;
    const int lane = tid & 63;
    const int wv   = tid >> 6;          // 0..7
    const int wrr  = (wv >> 2) * 64;    // wave row offset in tile (0/64)
    const int wc   = (wv & 3) * 64;     // wave col offset in tile
    const int lm   = lane & 15;
    const int q    = lane >> 4;         // k-granule 0..3

    // ---- swizzled read byte-offsets (A region [128][32], B region [256][32])
    int aOff[4], bOff[4];
    #pragma unroll
    for (int i = 0; i < 4; ++i) {
        const int r = wrr + i * 16 + lm;
        aOff[i] = r * 64 + ((q ^ ((r >> 1) & 3)) << 4);
    }
    #pragma unroll
    for (int j = 0; j < 4; ++j) {
        const int r = wc + j * 16 + lm;
        bOff[j] = r * 64 + ((q ^ ((r >> 1) & 3)) << 4);
    }

    // ---- staging: 3 gld16/thread; gld16 dest linear, swizzle pre-applied to
    // the GLOBAL k-granule (involution == its own inverse).
    const int rw = lane >> 2, qs = lane & 3;
    const int rA  = wv * 16 + rw;
    const int rB0 = wv * 32 + rw;
    const int rB1 = wv * 32 + 16 + rw;
    const u16* pA  = Ab + (long)rA  * lda + ((qs ^ ((rA  >> 1) & 3)) << 3);
    const u16* pB0 = Bb + (long)rB0 * ldb + ((qs ^ ((rB0 >> 1) & 3)) << 3);
    const u16* pB1 = Bb + (long)rB1 * ldb + ((qs ^ ((rB1 >> 1) & 3)) << 3);
    const int ldsA  = wv * 1024;
    const int ldsB0 = wv * 2048;
    const int ldsB1 = wv * 2048 + 1024;

#define STAGE(bufOff, kofs) { \
    gld16(pA  + (kofs), (u16*)(smem + (bufOff) + ldsA)); \
    gld16(pB0 + (kofs), (u16*)(smem + (bufOff) + 8192 + ldsB0)); \
    gld16(pB1 + (kofs), (u16*)(smem + (bufOff) + 8192 + ldsB1)); }

    f32x4 acc[4][4] = {};

    const int NT = K >> 5;             // K-steps of 32

    STAGE(0, 0);
    __syncthreads();                   // tile 0 resident (vmcnt+lgkm drained)

    for (int t = 0; t < NT; ++t) {
        const int bo = (t & 1) * 24576;
        const int bn = ((t + 1) & 1) * 24576;
        if (t + 1 < NT) STAGE(bn, (t + 1) * 32);

        bf16x8 a[4], b[4];
        const char* baseA = smem + bo;
        const char* baseB = smem + bo + 8192;
        #pragma unroll
        for (int i = 0; i < 4; ++i) a[i] = *(const bf16x8*)(baseA + aOff[i]);
        #pragma unroll
        for (int j = 0; j < 4; ++j) b[j] = *(const bf16x8*)(baseB + bOff[j]);

        #pragma unroll
        for (int i = 0; i < 4; ++i)
            #pragma unroll
            for (int j = 0; j < 4; ++j)
                acc[i][j] = __builtin_amdgcn_mfma_f32_16x16x32_bf16(
                    a[i], b[j], acc[i][j], 0, 0, 0);

        __syncthreads();               // reads done + next tile resident
    }

#undef STAGE

    // epilogue: per-wave LDS repack (16x65 fp32 each), optional resid add,
    // optional fused BN stats, coalesced bf16 stores
    float* rep = (float*)smem + wv * (16 * 65);
    const int rr = lane >> 2;
    const int cg = lane & 3;
    const int m0 = mt * 128;
    const int n0 = nt * 256;
    #pragma unroll
    for (int i = 0; i < 4; ++i) {      // row-frag: row = wrr + 16*i
        #pragma unroll
        for (int j = 0; j < 4; ++j) {  // col-frag: col = wc + 16*j
            const int col = 16 * j + lm;
            const float bj = BIAS ? b2f(bias[n0 + wc + col]) : 0.0f;
            #pragma unroll
            for (int r = 0; r < 4; ++r) {
                float v = acc[i][j][r] + bj;
                if (SOFTSIGN) v = v / (1.0f + fabsf(v));
                rep[(q * 4 + r) * 65 + col] = v;
            }
        }
        // intra-wave LDS RAW/WAR: wave-lockstep + per-wave buffer
        const int row = m0 + wrr + 16 * i + rr;
        const float* lr = rep + rr * 65 + cg * 16;
        float4 f0 = *(const float4*)(lr + 0);
        float4 f1 = *(const float4*)(lr + 4);
        float4 f2 = *(const float4*)(lr + 8);
        float4 f3 = *(const float4*)(lr + 12);
        if (RESID) {
            const u16* rp = RP + (long)row * ldc + n0 + wc + cg * 16;
            const ushort8v ra = *(const ushort8v*)rp;
            const ushort8v rb = *(const ushort8v*)(rp + 8);
            f0.x += b2f(ra[0]); f0.y += b2f(ra[1]); f0.z += b2f(ra[2]); f0.w += b2f(ra[3]);
            f1.x += b2f(ra[4]); f1.y += b2f(ra[5]); f1.z += b2f(ra[6]); f1.w += b2f(ra[7]);
            f2.x += b2f(rb[0]); f2.y += b2f(rb[1]); f2.z += b2f(rb[2]); f2.w += b2f(rb[3]);
            f3.x += b2f(rb[4]); f3.y += b2f(rb[5]); f3.z += b2f(rb[6]); f3.w += b2f(rb[7]);
        }
        if (STATS) {
            float s1 = (f0.x + f0.y + f0.z + f0.w) + (f1.x + f1.y + f1.z + f1.w)
                     + (f2.x + f2.y + f2.z + f2.w) + (f3.x + f3.y + f3.z + f3.w);
            float s2 = f0.x*f0.x + f0.y*f0.y + f0.z*f0.z + f0.w*f0.w
                     + f1.x*f1.x + f1.y*f1.y + f1.z*f1.z + f1.w*f1.w
                     + f2.x*f2.x + f2.y*f2.y + f2.z*f2.z + f2.w*f2.w
                     + f3.x*f3.x + f3.y*f3.y + f3.z*f3.z + f3.w*f3.w;
            s1 += __shfl_xor(s1, 1); s1 += __shfl_xor(s1, 2);
            s2 += __shfl_xor(s2, 1); s2 += __shfl_xor(s2, 2);
            if (cg == 0) {
                const int ch = row & (FC - 1);
                atomicAdd(&sp[ch], s1);
                atomicAdd(&sp[FC + ch], s2);
            }
        }
        ushort8v o0, o1;
        o0[0] = f2b(f0.x); o0[1] = f2b(f0.y); o0[2] = f2b(f0.z); o0[3] = f2b(f0.w);
        o0[4] = f2b(f1.x); o0[5] = f2b(f1.y); o0[6] = f2b(f1.z); o0[7] = f2b(f1.w);
        o1[0] = f2b(f2.x); o1[1] = f2b(f2.y); o1[2] = f2b(f2.z); o1[3] = f2b(f2.w);
        o1[4] = f2b(f3.x); o1[5] = f2b(f3.y); o1[6] = f2b(f3.z); o1[7] = f2b(f3.w);
        u16* cp = C + (long)row * ldc + n0 + wc + cg * 16;
        *(ushort8v*)cp = o0;
        *(ushort8v*)(cp + 8) = o1;
    }
}

// ---------------------------------------------------------------------------
// bf16 tiled transpose: src [R][Cc] -> dst [Cc][R] per batch
// ---------------------------------------------------------------------------
__global__ __launch_bounds__(256) void transpose_bf16(
    const u16* __restrict__ src, u16* __restrict__ dst,
    int R, int Cc, long sS, long sD)
{
    __shared__ u16 t[32][33];
    const int bz = blockIdx.z;
    src += (long)bz * sS;
    dst += (long)bz * sD;
    const int c0 = blockIdx.x * 32;
    const int r0 = blockIdx.y * 32;
    const int lx = threadIdx.x & 31;
    const int ly = threadIdx.x >> 5;   // 0..7
    #pragma unroll
    for (int d = 0; d < 32; d += 8)
        t[ly + d][lx] = src[(long)(r0 + ly + d) * Cc + c0 + lx];
    __syncthreads();
    #pragma unroll
    for (int d = 0; d < 32; d += 8)
        dst[(long)(c0 + ly + d) * R + r0 + lx] = t[lx][ly + d];
}

// ---------------------------------------------------------------------------
// transpose fused with BN apply: writes normalized value in-place (dstI) AND
// transposed (dstT). channel = source row (F dim). Bit-identical to the old
// separate bn_apply + transpose (same f2b once, then copy).
// ---------------------------------------------------------------------------
__global__ __launch_bounds__(256) void transpose_bn_bf16(
    const u16* __restrict__ src, u16* __restrict__ dstT,
    u16* __restrict__ dstI, const float* __restrict__ ssf,
    int R, int Cc, long sS, long sD)
{
    __shared__ u16 t[32][33];
    const int bz = blockIdx.z;
    src  += (long)bz * sS;
    dstI += (long)bz * sS;
    dstT += (long)bz * sD;
    const int c0 = blockIdx.x * 32;
    const int r0 = blockIdx.y * 32;
    const int lx = threadIdx.x & 31;
    const int ly = threadIdx.x >> 5;   // 0..7
    #pragma unroll
    for (int d = 0; d < 32; d += 8) {
        const int r = r0 + ly + d;
        const u16 nv = f2b(fmaf(b2f(src[(long)r * Cc + c0 + lx]),
                                ssf[r], ssf[FC + r]));
        t[ly + d][lx] = nv;
        dstI[(long)r * Cc + c0 + lx] = nv;
    }
    __syncthreads();
    #pragma unroll
    for (int d = 0; d < 32; d += 8)
        dstT[(long)(c0 + ly + d) * R + r0 + lx] = t[lx][ly + d];
}

// dst = src*scale+shift (+ add); optional fused stats of the OUTPUT (fp32,
// pre-rounding): one wave covers 256 contiguous elems = single channel at
// Lc=512, full-wave shfl reduce, one atomicAdd pair per wave per iter.
template<bool ADD, bool STATS>
__global__ __launch_bounds__(256) void bn_apply(
    const u16* __restrict__ src, const void* __restrict__ add,
    const int* __restrict__ addflag,
    const float* __restrict__ ss, void* __restrict__ dst,
    const int* __restrict__ outflag, long total4, int lcShift,
    float* __restrict__ sp)
{
    const bool addf32 = ADD && (addflag != nullptr) && (*addflag == 0);
    const bool outf32 = (outflag != nullptr) && (*outflag == 0);
    long i4 = (long)blockIdx.x * blockDim.x + threadIdx.x;
    const long stride = (long)gridDim.x * blockDim.x;
    for (; i4 < total4; i4 += stride) {
        const long i = i4 << 2;
        const int c = (int)((i >> lcShift) & (FC - 1));
        const float sc = ss[c];
        const float sh = ss[FC + c];
        const ushort4 v = *(const ushort4*)(src + i);
        float o0 = fmaf(b2f(v.x), sc, sh);
        float o1 = fmaf(b2f(v.y), sc, sh);
        float o2 = fmaf(b2f(v.z), sc, sh);
        float o3 = fmaf(b2f(v.w), sc, sh);
        if (ADD) {
            if (addf32) {
                const float4 a = *(const float4*)((const float*)add + i);
                o0 += a.x; o1 += a.y; o2 += a.z; o3 += a.w;
            } else {
                const ushort4 a = *(const ushort4*)((const u16*)add + i);
                o0 += b2f(a.x); o1 += b2f(a.y); o2 += b2f(a.z); o3 += b2f(a.w);
            }
        }
        if (STATS) {
            float s1 = o0 + o1 + o2 + o3;
            float s2 = o0 * o0 + o1 * o1 + o2 * o2 + o3 * o3;
            #pragma unroll
            for (int m = 1; m < 64; m <<= 1) {
                s1 += __shfl_xor(s1, m);
                s2 += __shfl_xor(s2, m);
            }
            if ((threadIdx.x & 63) == 0) {
                atomicAdd(&sp[c], s1);
                atomicAdd(&sp[FC + c], s2);
            }
        }
        if (outf32) {
            float4 o; o.x = o0; o.y = o1; o.z = o2; o.w = o3;
            *(float4*)((float*)dst + i) = o;
        } else {
            ushort4 o;
            o.x = f2b(o0); o.y = f2b(o1); o.z = f2b(o2); o.w = f2b(o3);
            *(ushort4*)((u16*)dst + i) = o;
        }
    }
}

extern "C" void kernel_launch(void* const* d_in, const int* in_sizes, int n_in,
                              void* d_out, int out_size, void* d_ws, size_t ws_size,
                              hipStream_t stream)
{
    const size_t MiB = (size_t)1 << 20;
    const long sFH = (long)FC * HH;        // 1,048,576 elems (2 MiB bf16)
    const long sFF = (long)FC * FC;        // 1,048,576
    const long sFD = (long)FC * DD;        //   524,288 (1 MiB)
    const long PE  = (long)NB * FC * DD;   // 16,777,216 (32 MiB)

    const size_t GLDS = 49152;             // 48 KiB dynamic LDS -> 2 blocks/CU
    static bool s_attr = false;
    if (!s_attr) {
        s_attr = true;
        hipFuncSetAttribute(reinterpret_cast<const void*>(&gemm128x256_nt<true, false, true, false>),
                            hipFuncAttributeMaxDynamicSharedMemorySize, (int)GLDS);
        hipFuncSetAttribute(reinterpret_cast<const void*>(&gemm128x256_nt<false, true, false, false>),
                            hipFuncAttributeMaxDynamicSharedMemorySize, (int)GLDS);
        hipFuncSetAttribute(reinterpret_cast<const void*>(&gemm128x256_nt<false, false, false, false>),
                            hipFuncAttributeMaxDynamicSharedMemorySize, (int)GLDS);
        hipFuncSetAttribute(reinterpret_cast<const void*>(&gemm128x256_nt<true, false, true, true>),
                            hipFuncAttributeMaxDynamicSharedMemorySize, (int)GLDS);
    }

    // bf16 param packing offsets
    long off[16];
    long cur = 0;
    for (int i = 1; i < 15; ++i) { off[i] = cur; cur += ((long)in_sizes[i] + 7) & ~7L; }
    const size_t paramBytes = (size_t)cur * 2;

    // adaptive correlation chunk: scratch = cb*6 MiB (VT + W + V2)
    int cb = 32;
    while (cb > 1 &&
           64 * MiB + (size_t)cb * 6 * MiB + paramBytes + 65536 > ws_size)
        cb >>= 1;

    // ---- workspace layout ----
    u16* V   = (u16*)d_ws;                          // 64 MiB: v (N,F,H)
    u16* VT  = (u16*)((char*)d_ws + 64 * MiB);      // cb*2 MiB: v^T chunk
    u16* WW  = VT + (long)cb * sFH;                 // cb*2 MiB: w chunk
    u16* V2  = WW + (long)cb * sFF;                 // cb*2 MiB: v2 chunk
    u16* WC  = V2 + (long)cb * sFH;                 // packed bf16 params
    char* tail = (char*)(WC + cur);
    tail = (char*)(((uintptr_t)tail + 255) & ~(uintptr_t)255);
    float* SP0  = (float*)tail;                     // 4 stage partial buffers
    float* SP1  = SP0 + 2 * FC;
    float* SP2  = SP1 + 2 * FC;
    float* SP3  = SP2 + 2 * FC;
    float* SSF  = SP3 + 2 * FC;                     // folded (scale,shift)
    int*   FLAG = (int*)(SSF + 2 * FC);
    // d_out (fp32 out => 64 MiB): lower 32 MiB = VX (v3->s->xr), upper = XB
    u16* VX  = (u16*)d_out;
    u16* XB  = (u16*)d_out + PE;                    // x as bf16
    u16* V4  = V;                                   // v4/t (N,F,D) reuses V
    u16* XRT = V + PE;                              // xr^T reuses V upper half

    const dim3 blk(256);
    const dim3 blk512(512);
    const dim3 egrid(4096);

    // 0. detect dtype; zero stats partials; convert params + x to bf16
    detect_dtype<<<1, blk, 0, stream>>>((const u32*)d_in[0], FLAG);
    zero_partials<<<dim3(32), blk, 0, stream>>>(SP0);   // zeros SP0..SP3 (8*FC)
    ConvArgs ca;
    for (int i = 1; i < 15; ++i) {
        ca.src[i - 1] = d_in[i];
        ca.off[i - 1] = off[i];
        ca.n4[i - 1]  = (long)in_sizes[i] / 4;
    }
    convert_params<<<dim3(256), blk, 0, stream>>>(ca, WC, FLAG);
    convert_to_bf16<<<dim3(1024), blk, 0, stream>>>(d_in[0], XB, PE / 4, FLAG);

    const u16* W0c = WC + off[1];
    const u16* b0c = WC + off[2];
    const u16* g0c = WC + off[3];
    const u16* be0c = WC + off[4];
    const u16* W1c = WC + off[5];
    const u16* b1c = WC + off[6];
    const u16* g1c = WC + off[7];
    const u16* be1c = WC + off[8];
    const u16* gfc = WC + off[9];
    const u16* bfc = WC + off[10];
    const u16* Wcc = WC + off[11];
    const u16* bcc = WC + off[12];
    const u16* goc = WC + off[13];
    const u16* boc = WC + off[14];

    // 1. v = x @ W0^T + b0  (BN0 stats fused into epilogue -> SP0)
    gemm128x256_nt<true, false, true, false><<<dim3(HH / 256, (NB * FC) / 128, 1), blk512, GLDS, stream>>>(
        XB, W0c, b0c, nullptr, V, SP0, NB * FC, HH, DD, DD, DD, HH, 0, 0, 0);
    fold_bn<<<dim3(4), blk, 0, stream>>>(SP0, g0c, be0c, SSF, 1.0f / (float)(NB * HH));

    // 2-5 per chunk: vT+BN0-apply (V in place + VT); w = softsign(v v^T);
    // v2 = w @ v (via vT); v3 = v2 @ W1^T + b1 (BN1 stats fused -> SP1)
    for (int bz0 = 0; bz0 < NB; bz0 += cb) {
        const int c = (NB - bz0 < cb) ? (NB - bz0) : cb;
        transpose_bn_bf16<<<dim3(HH / 32, FC / 32, c), blk, 0, stream>>>(
            V + bz0 * sFH, VT, V + bz0 * sFH, SSF, FC, HH, sFH, sFH);
        gemm128x256_nt<false, true, false, false><<<dim3(FC / 256, FC / 128, c), blk512, GLDS, stream>>>(
            V + bz0 * sFH, V + bz0 * sFH, nullptr, nullptr, WW, nullptr,
            FC, FC, HH, HH, HH, FC, sFH, sFH, sFF);
        gemm128x256_nt<false, false, false, false><<<dim3(HH / 256, FC / 128, c), blk512, GLDS, stream>>>(
            WW, VT, nullptr, nullptr, V2, nullptr,
            FC, HH, FC, FC, FC, HH, sFF, sFH, sFH);
        gemm128x256_nt<true, false, true, false><<<dim3(DD / 256, (c * FC) / 128, 1), blk512, GLDS, stream>>>(
            V2, W1c, b1c, nullptr, VX + bz0 * sFD, SP1,
            c * FC, DD, HH, HH, HH, DD, 0, 0, 0);
    }
    fold_bn<<<dim3(4), blk, 0, stream>>>(SP1, g1c, be1c, SSF, 1.0f / (float)(NB * DD));

    // 6. s = BN1(v3) + x   (in place VX; s-stats for BNf fused -> SP2)
    bn_apply<true, true><<<egrid, blk, 0, stream>>>(
        VX, XB, nullptr, SSF, VX, nullptr, PE / 4, 9, SP2);
    fold_bn<<<dim3(4), blk, 0, stream>>>(SP2, gfc, bfc, SSF, 1.0f / (float)(NB * DD));

    // 7. xr = BNf(s)       (in place VX)
    bn_apply<false, false><<<egrid, blk, 0, stream>>>(
        VX, nullptr, nullptr, SSF, VX, nullptr, PE / 4, 9, nullptr);

    // 8. xr^T, then t = Wc @ xr + bc + xr (resid+bias+BNo-stats fused) -> V4
    transpose_bf16<<<dim3(DD / 32, FC / 32, NB), blk, 0, stream>>>(
        VX, XRT, FC, DD, sFD, sFD);
    gemm128x256_nt<true, false, true, true><<<dim3(DD / 256, FC / 128, NB), blk512, GLDS, stream>>>(
        Wcc, XRT, bcc, VX, V4, SP3, FC, DD, FC, FC, FC, DD, 0, sFD, sFD);
    fold_bn<<<dim3(4), blk, 0, stream>>>(SP3, goc, boc, SSF, 1.0f / (float)(NB * DD));

    // 9. out = BNo(t); out dtype per FLAG
    bn_apply<false, false><<<egrid, blk, 0, stream>>>(
        V4, nullptr, nullptr, SSF, d_out, FLAG, PE / 4, 9, nullptr);
}